// Round 3
// baseline (32198.044 us; speedup 1.0000x reference)
//
#include <hip/hip_runtime.h>
#include <math.h>

#define NS0 80000
#define NS1 60000
#define NS2 30000
#define NTOT 170000
#define OFF1 80000
#define OFF2 140000

// ---- bulk scratch as a device global (ws_size proved too small in R0/R1) ----
// Layout needs ~243.7M floats; allocate 244M (~976 MB of HBM, allocated at
// module load — NOT inside kernel_launch, so graph capture is unaffected).
__device__ float g_ws[244000000];

__device__ inline float gelu_f(float x) {
  float x3 = x * x * x;
  return 0.5f * x * (1.0f + tanhf(0.7978845608028654f * (x + 0.044715f * x3)));
}

__device__ inline void atomicMaxF(float* addr, float val) {
  int* ai = (int*)addr;
  int old = __float_as_int(*addr);
  while (__int_as_float(old) < val) {
    int assumed = old;
    old = atomicCAS(ai, assumed, __float_as_int(val));
    if (old == assumed) break;
  }
}

// ---------------- generic fp32 GEMM: C[M x N] = (accum? C:0) + A[M x K] * W[K x N] + bias ----
__global__ __launch_bounds__(256) void gemm128(
    const float* __restrict__ A, int lda,
    const float* __restrict__ W, int ldw,
    const float* __restrict__ bias,
    float* __restrict__ C, int ldc,
    int M, int K, int accum)
{
  __shared__ float As[16][132];
  __shared__ float Bs[16][64];
  const int tid = threadIdx.x;
  const int tx = tid & 15;
  const int ty = tid >> 4;
  const int row0 = blockIdx.x * 128;
  const int col0 = blockIdx.y * 64;
  const int arow = tid >> 2;
  const int ak = (tid & 3) << 2;
  const int bk = tid >> 4;
  const int bn = (tid & 15) << 2;

  float acc[8][4];
#pragma unroll
  for (int i = 0; i < 8; ++i)
#pragma unroll
    for (int j = 0; j < 4; ++j) acc[i][j] = 0.f;

  for (int k0 = 0; k0 < K; k0 += 16) {
#pragma unroll
    for (int half = 0; half < 2; ++half) {
      int r = row0 + arow + half * 64;
      float4 av = make_float4(0.f, 0.f, 0.f, 0.f);
      if (r < M) av = *(const float4*)(A + (size_t)r * lda + k0 + ak);
      As[ak + 0][arow + half * 64] = av.x;
      As[ak + 1][arow + half * 64] = av.y;
      As[ak + 2][arow + half * 64] = av.z;
      As[ak + 3][arow + half * 64] = av.w;
    }
    float4 bv = *(const float4*)(W + (size_t)(k0 + bk) * ldw + col0 + bn);
    *(float4*)&Bs[bk][bn] = bv;
    __syncthreads();
#pragma unroll
    for (int kk = 0; kk < 16; ++kk) {
      float4 b4 = *(const float4*)&Bs[kk][tx << 2];
      float4 a0 = *(const float4*)&As[kk][ty << 3];
      float4 a1 = *(const float4*)&As[kk][(ty << 3) + 4];
      float a[8] = {a0.x, a0.y, a0.z, a0.w, a1.x, a1.y, a1.z, a1.w};
      float b[4] = {b4.x, b4.y, b4.z, b4.w};
#pragma unroll
      for (int i = 0; i < 8; ++i)
#pragma unroll
        for (int j = 0; j < 4; ++j)
          acc[i][j] = fmaf(a[i], b[j], acc[i][j]);
    }
    __syncthreads();
  }
  float4 bias4 = make_float4(0.f, 0.f, 0.f, 0.f);
  if (bias) bias4 = *(const float4*)(bias + col0 + (tx << 2));
#pragma unroll
  for (int i = 0; i < 8; ++i) {
    int r = row0 + (ty << 3) + i;
    if (r < M) {
      float* cp = C + (size_t)r * ldc + col0 + (tx << 2);
      float4 o;
      o.x = acc[i][0] + bias4.x;
      o.y = acc[i][1] + bias4.y;
      o.z = acc[i][2] + bias4.z;
      o.w = acc[i][3] + bias4.w;
      if (accum) {
        float4 c = *(const float4*)cp;
        o.x += c.x; o.y += c.y; o.z += c.z; o.w += c.w;
      }
      *(float4*)cp = o;
    }
  }
}

// ---------------- LayerNorm: one wave per row of 256 ----------------
__global__ __launch_bounds__(256) void ln_kernel(
    const float* __restrict__ X,
    const float* __restrict__ g, const float* __restrict__ b,
    float* __restrict__ H)
{
  int w = (blockIdx.x * blockDim.x + threadIdx.x) >> 6;
  int lane = threadIdx.x & 63;
  if (w >= NTOT) return;
  int type = (w < NS0) ? 0 : (w < OFF2 ? 1 : 2);
  float4 x = *(const float4*)(X + (size_t)w * 256 + (lane << 2));
  float s = x.x + x.y + x.z + x.w;
  float q = x.x * x.x + x.y * x.y + x.z * x.z + x.w * x.w;
#pragma unroll
  for (int off = 32; off >= 1; off >>= 1) {
    s += __shfl_xor(s, off);
    q += __shfl_xor(q, off);
  }
  float m = s * (1.f / 256.f);
  float var = q * (1.f / 256.f) - m * m;
  float rs = rsqrtf(var + 1e-5f);
  float4 gg = *(const float4*)(g + type * 256 + (lane << 2));
  float4 bb = *(const float4*)(b + type * 256 + (lane << 2));
  float4 o;
  o.x = (x.x - m) * rs * gg.x + bb.x;
  o.y = (x.y - m) * rs * gg.y + bb.y;
  o.z = (x.z - m) * rs * gg.z + bb.z;
  o.w = (x.w - m) * rs * gg.w + bb.w;
  *(float4*)(H + (size_t)w * 256 + (lane << 2)) = o;
}

// ---------------- edge scores: one wave per edge ----------------
__global__ __launch_bounds__(256) void edge_scores(
    const int* __restrict__ ei, int ne,
    const float* __restrict__ Q, int dst_off,
    const float* __restrict__ KR,
    const float* __restrict__ prel,
    float* __restrict__ SC, size_t sc_off,
    float* __restrict__ AMX)
{
  int w = (blockIdx.x * blockDim.x + threadIdx.x) >> 6;
  int lane = threadIdx.x & 63;
  if (w >= ne) return;
  int src = ei[w];
  int dst = ei[ne + w];
  float4 q4 = *(const float4*)(Q + (size_t)(dst_off + dst) * 256 + (lane << 2));
  float4 k4 = *(const float4*)(KR + (size_t)src * 256 + (lane << 2));
  float s = q4.x * k4.x + q4.y * k4.y + q4.z * k4.z + q4.w * k4.w;
  s += __shfl_xor(s, 8, 16);
  s += __shfl_xor(s, 4, 16);
  s += __shfl_xor(s, 2, 16);
  s += __shfl_xor(s, 1, 16);
  int h = lane >> 4;
  if ((lane & 15) == 0) {
    float a = s * prel[h] * 0.125f;
    SC[(sc_off + w) * 4 + h] = a;
    atomicMaxF(&AMX[(size_t)(dst_off + dst) * 4 + h], a);
  }
}

// ---------------- exp + segment-sum ----------------
__global__ __launch_bounds__(256) void edge_expz(
    const int* __restrict__ ei, int ne, int dst_off,
    float* __restrict__ SC, size_t sc_off,
    const float* __restrict__ AMX, float* __restrict__ Z)
{
  int t = blockIdx.x * blockDim.x + threadIdx.x;
  if (t >= ne * 4) return;
  int e = t >> 2, h = t & 3;
  int dst = ei[ne + e];
  size_t seg = (size_t)(dst_off + dst);
  float a = SC[(sc_off + e) * 4 + h];
  float ex = expf(a - AMX[seg * 4 + h]);
  SC[(sc_off + e) * 4 + h] = ex;
  atomicAdd(&Z[seg * 4 + h], ex);
}

// ---------------- messages: one wave per edge, atomic scatter ----------------
__global__ __launch_bounds__(256) void edge_msg(
    const int* __restrict__ ei, int ne, int dst_off,
    const float* __restrict__ VR,
    const float* __restrict__ SC, size_t sc_off,
    const float* __restrict__ Z, float* __restrict__ AGG)
{
  int w = (blockIdx.x * blockDim.x + threadIdx.x) >> 6;
  int lane = threadIdx.x & 63;
  if (w >= ne) return;
  int src = ei[w];
  int dst = ei[ne + w];
  size_t seg = (size_t)(dst_off + dst);
  int h = lane >> 4;
  float attn = SC[(sc_off + w) * 4 + h] / (Z[seg * 4 + h] + 1e-16f);
  float4 v4 = *(const float4*)(VR + (size_t)src * 256 + (lane << 2));
  float* dp = AGG + seg * 256 + (lane << 2);
  atomicAdd(dp + 0, v4.x * attn);
  atomicAdd(dp + 1, v4.y * attn);
  atomicAdd(dp + 2, v4.z * attn);
  atomicAdd(dp + 3, v4.w * attn);
}

__global__ __launch_bounds__(256) void gelu_ip(float* __restrict__ p, int n4) {
  int t = blockIdx.x * blockDim.x + threadIdx.x;
  if (t >= n4) return;
  float4 v = ((float4*)p)[t];
  v.x = gelu_f(v.x); v.y = gelu_f(v.y); v.z = gelu_f(v.z); v.w = gelu_f(v.w);
  ((float4*)p)[t] = v;
}

// Xcur = alpha*TMP + (1-alpha)*Hb
__global__ __launch_bounds__(256) void skip_store(
    const float* __restrict__ TMP, const float* __restrict__ Hb,
    const float* __restrict__ skipv, float* __restrict__ Xcur)
{
  int t = blockIdx.x * blockDim.x + threadIdx.x;
  if (t >= NTOT * 64) return;
  int w = t >> 6;
  int f4 = (t & 63) << 2;
  int type = (w < NS0) ? 0 : (w < OFF2 ? 1 : 2);
  float al = 1.f / (1.f + expf(-skipv[type]));
  float4 a = *(const float4*)(TMP + (size_t)w * 256 + f4);
  float4 h = *(const float4*)(Hb + (size_t)w * 256 + f4);
  float4 o;
  o.x = al * a.x + (1.f - al) * h.x;
  o.y = al * a.y + (1.f - al) * h.y;
  o.z = al * a.z + (1.f - al) * h.z;
  o.w = al * a.w + (1.f - al) * h.w;
  *(float4*)(Xcur + (size_t)w * 256 + f4) = o;
}

__global__ void fill_kernel(float* __restrict__ p, float v, int n) {
  int i = blockIdx.x * blockDim.x + threadIdx.x;
  if (i < n) p[i] = v;
}

// ---------------- pooling ----------------
__global__ __launch_bounds__(256) void gate_score(
    const float* __restrict__ JK, const float* __restrict__ Wg, const float* __restrict__ bg,
    const int* __restrict__ batch, float* __restrict__ GS, float* __restrict__ GMX, int n)
{
  int w = (blockIdx.x * blockDim.x + threadIdx.x) >> 6;
  int lane = threadIdx.x & 63;
  if (w >= n) return;
  float4 x = *(const float4*)(JK + (size_t)w * 256 + (lane << 2));
  float4 g4 = *(const float4*)(Wg + (lane << 2));
  float s = x.x * g4.x + x.y * g4.y + x.z * g4.z + x.w * g4.w;
#pragma unroll
  for (int off = 32; off >= 1; off >>= 1) s += __shfl_xor(s, off);
  if (lane == 0) {
    float v = s + bg[0];
    GS[w] = v;
    atomicMaxF(&GMX[batch[w]], v);
  }
}

__global__ __launch_bounds__(256) void gate_expz(
    float* __restrict__ GS, const float* __restrict__ GMX, float* __restrict__ GZ,
    const int* __restrict__ batch, int n)
{
  int w = blockIdx.x * blockDim.x + threadIdx.x;
  if (w >= n) return;
  int b = batch[w];
  float e = expf(GS[w] - GMX[b]);
  GS[w] = e;
  atomicAdd(&GZ[b], e);
}

__global__ __launch_bounds__(256) void pool_kernel(
    const float* __restrict__ JK, const float* __restrict__ GS, const float* __restrict__ GZ,
    const int* __restrict__ batch, float* __restrict__ O784, int colOff, int n)
{
  int w = (blockIdx.x * blockDim.x + threadIdx.x) >> 6;
  int lane = threadIdx.x & 63;
  if (w >= n) return;
  int b = batch[w];
  float wt = GS[w] / (GZ[b] + 1e-16f);
  float4 x = *(const float4*)(JK + (size_t)w * 256 + (lane << 2));
  float* dp = O784 + (size_t)b * 784 + colOff + (lane << 2);
  atomicAdd(dp + 0, x.x * wt);
  atomicAdd(dp + 1, x.y * wt);
  atomicAdd(dp + 2, x.z * wt);
  atomicAdd(dp + 3, x.w * wt);
}

__global__ void hy_kernel(
    const float* __restrict__ y, const float* __restrict__ W1, const float* __restrict__ b1,
    const float* __restrict__ W2, const float* __restrict__ b2, float* __restrict__ O784)
{
  int r = threadIdx.x;
  if (r >= 64) return;
  float yv = y[r];
  float h1[16];
#pragma unroll
  for (int j = 0; j < 16; ++j) {
    float v = yv * W1[j] + b1[j];
    h1[j] = v > 0.f ? v : 0.2f * v;
  }
#pragma unroll
  for (int c = 0; c < 16; ++c) {
    float s = b2[c];
#pragma unroll
    for (int j = 0; j < 16; ++j) s += h1[j] * W2[j * 16 + c];
    O784[(size_t)r * 784 + 768 + c] = s;
  }
}

__global__ void dense_small(
    const float* __restrict__ A, int K, int N,
    const float* __restrict__ W, const float* __restrict__ b, float* __restrict__ C)
{
  int r = blockIdx.x;
  int c = threadIdx.x;
  if (c >= N) return;
  float s = b[c];
  for (int k = 0; k < K; ++k) s += A[(size_t)r * K + k] * W[(size_t)k * N + c];
  C[(size_t)r * N + c] = s;
}

__global__ void bn_gelu(
    const float* __restrict__ in, const float* __restrict__ g, const float* __restrict__ be,
    float* __restrict__ out, int C)
{
  int c = threadIdx.x;
  if (c >= C) return;
  float s = 0.f, sq = 0.f;
  for (int r = 0; r < 64; ++r) {
    float v = in[r * C + c];
    s += v;
    sq += v * v;
  }
  float m = s * (1.f / 64.f);
  float var = sq * (1.f / 64.f) - m * m;
  float rs = rsqrtf(var + 1e-5f);
  for (int r = 0; r < 64; ++r) {
    float v = (in[r * C + c] - m) * rs * g[c] + be[c];
    out[r * C + c] = gelu_f(v);
  }
}

extern "C" void kernel_launch(void* const* d_in, const int* in_sizes, int n_in,
                              void* d_out, int out_size, void* d_ws, size_t ws_size,
                              hipStream_t stream)
{
  const float* x_in[3] = {(const float*)d_in[0], (const float*)d_in[1], (const float*)d_in[2]};
  const float* y_base = (const float*)d_in[3];
  const float* W_in = (const float*)d_in[4];
  const float* b_in = (const float*)d_in[5];
  const float* ln_g = (const float*)d_in[6];
  const float* ln_b = (const float*)d_in[7];
  const float* W_kqv = (const float*)d_in[8];
  const float* b_kqv = (const float*)d_in[9];
  const float* W_krel = (const float*)d_in[10];
  const float* W_vrel = (const float*)d_in[11];
  const float* p_rel = (const float*)d_in[12];
  const float* W_out = (const float*)d_in[13];
  const float* b_out = (const float*)d_in[14];
  const float* skipv = (const float*)d_in[15];
  const float* W_jk = (const float*)d_in[16];
  const float* b_jk = (const float*)d_in[17];
  const float* W_gate = (const float*)d_in[18];
  const float* b_gate = (const float*)d_in[19];
  const float* W_y1 = (const float*)d_in[20];
  const float* b_y1 = (const float*)d_in[21];
  const float* W_y2 = (const float*)d_in[22];
  const float* b_y2 = (const float*)d_in[23];
  const float* Wg1 = (const float*)d_in[24];
  const float* bg1 = (const float*)d_in[25];
  const float* g1 = (const float*)d_in[26];
  const float* beta1 = (const float*)d_in[27];
  const float* Wg2 = (const float*)d_in[28];
  const float* bg2 = (const float*)d_in[29];
  const float* g2 = (const float*)d_in[30];
  const float* beta2 = (const float*)d_in[31];
  const float* Wg3 = (const float*)d_in[32];
  const float* bg3 = (const float*)d_in[33];
  const int* eis[4] = {(const int*)d_in[34], (const int*)d_in[35], (const int*)d_in[36], (const int*)d_in[37]};
  const int* batchp[3] = {(const int*)d_in[38], (const int*)d_in[39], (const int*)d_in[40]};

  const int NSs[3] = {NS0, NS1, NS2};
  const int offs[3] = {0, OFF1, OFF2};
  const int NEs[4] = {320000, 320000, 160000, 160000};
  const int stt[4] = {0, 1, 0, 2};
  const int dtt[4] = {1, 0, 2, 0};
  const size_t scoff[4] = {0, 320000, 640000, 800000};

  // ---- resolve bulk scratch: device-global symbol (ws_size proved too small) ----
  float* ws = nullptr;
  if (hipGetSymbolAddress((void**)&ws, HIP_SYMBOL(g_ws)) != hipSuccess || !ws) {
    ws = (float*)d_ws;  // fallback; only valid if ws_size is large enough
    if (ws_size < (size_t)244000000 * sizeof(float)) return;
  }

  size_t o = 0;
  float* Xcur = ws + o;  o += (size_t)NTOT * 256;   // current xs
  float* Hb = ws + o;    o += (size_t)NTOT * 256;   // LN output
  float* QA = ws + o;    o += (size_t)NTOT * 256;   // q, then reused as AGG (f32 atomics)
  float* KV = ws + o;    o += (size_t)NTOT * 256;   // k, then v, then W_out-output
  float* JKacc = ws + o; o += (size_t)NTOT * 256;   // JK accumulator
  float* KRV = ws + o;   o += (size_t)80000 * 256;  // per-edge-type k_rel / v_rel
  float* SC = ws + o;    o += (size_t)960000 * 4;
  float* AMX = ws + o;   o += (size_t)NTOT * 4;
  float* Zb = ws + o;    o += (size_t)NTOT * 4;
  float* GS = ws + o;    o += (size_t)NTOT;
  float* GMX = ws + o;   o += 192;
  float* GZ = ws + o;    o += 192;
  float* O784 = ws + o;  o += (size_t)64 * 784;
  float* BN1 = ws + o;   o += (size_t)64 * 256;
  float* T1 = ws + o;    o += (size_t)64 * 256;
  float* BN2 = ws + o;   o += (size_t)64 * 128;
  float* T2 = ws + o;    o += (size_t)64 * 128;

  auto gemm = [&](const float* A, int lda, const float* W, int ldw, const float* bias,
                  float* C, int ldc, int M, int N, int K, int accum) {
    dim3 g((M + 127) / 128, N / 64);
    gemm128<<<g, 256, 0, stream>>>(A, lda, W, ldw, bias, C, ldc, M, K, accum);
  };

  // input projection -> Xcur
  for (int i = 0; i < 3; ++i)
    gemm(x_in[i], 128, W_in + (size_t)i * 128 * 256, 256, b_in + i * 256,
         Xcur + (size_t)offs[i] * 256, 256, NSs[i], 256, 128, 0);

  for (int l = 0; l < 4; ++l) {
    ln_kernel<<<(NTOT * 64 + 255) / 256, 256, 0, stream>>>(
        Xcur, ln_g + (size_t)l * 3 * 256, ln_b + (size_t)l * 3 * 256, Hb);

    // k -> KV, q -> QA (column slices of W_kqv)
    for (int i = 0; i < 3; ++i) {
      const float* Wb = W_kqv + ((size_t)l * 3 + i) * 256 * 768;
      const float* bb = b_kqv + ((size_t)l * 3 + i) * 768;
      gemm(Hb + (size_t)offs[i] * 256, 256, Wb, 768, bb,
           KV + (size_t)offs[i] * 256, 256, NSs[i], 256, 256, 0);          // k
      gemm(Hb + (size_t)offs[i] * 256, 256, Wb + 256, 768, bb + 256,
           QA + (size_t)offs[i] * 256, 256, NSs[i], 256, 256, 0);          // q
    }

    hipMemsetAsync(Zb, 0, (size_t)NTOT * 4 * sizeof(float), stream);
    fill_kernel<<<(NTOT * 4 + 255) / 256, 256, 0, stream>>>(AMX, -INFINITY, NTOT * 4);

    // scores
    for (int e = 0; e < 4; ++e) {
      gemm(KV + (size_t)offs[stt[e]] * 256, 256,
           W_krel + ((size_t)l * 4 + e) * 256 * 256, 256, nullptr,
           KRV, 256, NSs[stt[e]], 256, 256, 0);
      edge_scores<<<(NEs[e] * 64 + 255) / 256, 256, 0, stream>>>(
          eis[e], NEs[e], QA, offs[dtt[e]], KRV, p_rel + ((size_t)l * 4 + e) * 4, SC, scoff[e], AMX);
    }
    for (int e = 0; e < 4; ++e)
      edge_expz<<<(NEs[e] * 4 + 255) / 256, 256, 0, stream>>>(
          eis[e], NEs[e], offs[dtt[e]], SC, scoff[e], AMX, Zb);

    // q dead: QA becomes AGG
    hipMemsetAsync(QA, 0, (size_t)NTOT * 256 * sizeof(float), stream);

    // v -> KV (k dead)
    for (int i = 0; i < 3; ++i) {
      const float* Wb = W_kqv + ((size_t)l * 3 + i) * 256 * 768;
      const float* bb = b_kqv + ((size_t)l * 3 + i) * 768;
      gemm(Hb + (size_t)offs[i] * 256, 256, Wb + 512, 768, bb + 512,
           KV + (size_t)offs[i] * 256, 256, NSs[i], 256, 256, 0);          // v
    }
    // messages
    for (int e = 0; e < 4; ++e) {
      gemm(KV + (size_t)offs[stt[e]] * 256, 256,
           W_vrel + ((size_t)l * 4 + e) * 256 * 256, 256, nullptr,
           KRV, 256, NSs[stt[e]], 256, 256, 0);
      edge_msg<<<(NEs[e] * 64 + 255) / 256, 256, 0, stream>>>(
          eis[e], NEs[e], offs[dtt[e]], KRV, SC, scoff[e], Zb, QA);
    }
    // gelu + W_out -> KV (v dead)
    gelu_ip<<<(NTOT * 64 + 255) / 256, 256, 0, stream>>>(QA, NTOT * 64);
    for (int i = 0; i < 3; ++i)
      gemm(QA + (size_t)offs[i] * 256, 256, W_out + ((size_t)l * 3 + i) * 256 * 256, 256,
           b_out + ((size_t)l * 3 + i) * 256, KV + (size_t)offs[i] * 256, 256, NSs[i], 256, 256, 0);
    // skip -> Xcur
    skip_store<<<(NTOT * 64 + 255) / 256, 256, 0, stream>>>(KV, Hb, skipv + l * 3, Xcur);

    // JKacc (+)= Xcur @ W_jk[l-slice]; bias on first layer
    for (int i = 0; i < 3; ++i)
      gemm(Xcur + (size_t)offs[i] * 256, 256,
           W_jk + (size_t)i * 1024 * 256 + (size_t)l * 256 * 256, 256,
           (l == 0) ? (b_jk + i * 256) : nullptr,
           JKacc + (size_t)offs[i] * 256, 256, NSs[i], 256, 256, (l == 0) ? 0 : 1);
  }

  // gated pooling over JKacc
  hipMemsetAsync(GZ, 0, 192 * sizeof(float), stream);
  hipMemsetAsync(O784, 0, (size_t)64 * 784 * sizeof(float), stream);
  fill_kernel<<<1, 192, 0, stream>>>(GMX, -INFINITY, 192);
  for (int i = 0; i < 3; ++i)
    gate_score<<<(NSs[i] * 64 + 255) / 256, 256, 0, stream>>>(
        JKacc + (size_t)offs[i] * 256, W_gate + i * 256, b_gate + i, batchp[i],
        GS + offs[i], GMX + i * 64, NSs[i]);
  for (int i = 0; i < 3; ++i)
    gate_expz<<<(NSs[i] + 255) / 256, 256, 0, stream>>>(
        GS + offs[i], GMX + i * 64, GZ + i * 64, batchp[i], NSs[i]);
  for (int i = 0; i < 3; ++i)
    pool_kernel<<<(NSs[i] * 64 + 255) / 256, 256, 0, stream>>>(
        JKacc + (size_t)offs[i] * 256, GS + offs[i], GZ + i * 64, batchp[i], O784, i * 256, NSs[i]);

  hy_kernel<<<1, 64, 0, stream>>>(y_base, W_y1, b_y1, W_y2, b_y2, O784);

  // head MLP
  dense_small<<<64, 256, 0, stream>>>(O784, 784, 256, Wg1, bg1, BN1);
  bn_gelu<<<1, 256, 0, stream>>>(BN1, g1, beta1, T1, 256);
  dense_small<<<64, 128, 0, stream>>>(T1, 256, 128, Wg2, bg2, BN2);
  bn_gelu<<<1, 128, 0, stream>>>(BN2, g2, beta2, T2, 128);
  dense_small<<<64, 1, 0, stream>>>(T2, 128, 1, Wg3, bg3, (float*)d_out);
}

// Round 4
// 19778.517 us; speedup vs baseline: 1.6279x; 1.6279x over previous
//
#include <hip/hip_runtime.h>
#include <math.h>

#define NS0 80000
#define NS1 60000
#define NS2 30000
#define NTOT 170000
#define OFF1 80000
#define OFF2 140000

// ---- bulk scratch as a device global (harness ws_size too small; allocated at
// module load, not inside kernel_launch, so graph capture is unaffected) ----
__device__ float g_ws[310000000];  // ~1.24 GB

__device__ inline float gelu_f(float x) {
  float x3 = x * x * x;
  return 0.5f * x * (1.0f + tanhf(0.7978845608028654f * (x + 0.044715f * x3)));
}

__device__ inline void atomicMaxF(float* addr, float val) {
  int* ai = (int*)addr;
  int old = __float_as_int(*addr);
  while (__int_as_float(old) < val) {
    int assumed = old;
    old = atomicCAS(ai, assumed, __float_as_int(val));
    if (old == assumed) break;
  }
}

// ---------------- generic fp32 GEMM: C[M x N] = (accum? C:0) + A[M x K] * W[K x N] + bias ----
__global__ __launch_bounds__(256) void gemm128(
    const float* __restrict__ A, int lda,
    const float* __restrict__ W, int ldw,
    const float* __restrict__ bias,
    float* __restrict__ C, int ldc,
    int M, int K, int accum)
{
  __shared__ float As[16][132];
  __shared__ float Bs[16][64];
  const int tid = threadIdx.x;
  const int tx = tid & 15;
  const int ty = tid >> 4;
  const int row0 = blockIdx.x * 128;
  const int col0 = blockIdx.y * 64;
  const int arow = tid >> 2;
  const int ak = (tid & 3) << 2;
  const int bk = tid >> 4;
  const int bn = (tid & 15) << 2;

  float acc[8][4];
#pragma unroll
  for (int i = 0; i < 8; ++i)
#pragma unroll
    for (int j = 0; j < 4; ++j) acc[i][j] = 0.f;

  for (int k0 = 0; k0 < K; k0 += 16) {
#pragma unroll
    for (int half = 0; half < 2; ++half) {
      int r = row0 + arow + half * 64;
      float4 av = make_float4(0.f, 0.f, 0.f, 0.f);
      if (r < M) av = *(const float4*)(A + (size_t)r * lda + k0 + ak);
      As[ak + 0][arow + half * 64] = av.x;
      As[ak + 1][arow + half * 64] = av.y;
      As[ak + 2][arow + half * 64] = av.z;
      As[ak + 3][arow + half * 64] = av.w;
    }
    float4 bv = *(const float4*)(W + (size_t)(k0 + bk) * ldw + col0 + bn);
    *(float4*)&Bs[bk][bn] = bv;
    __syncthreads();
#pragma unroll
    for (int kk = 0; kk < 16; ++kk) {
      float4 b4 = *(const float4*)&Bs[kk][tx << 2];
      float4 a0 = *(const float4*)&As[kk][ty << 3];
      float4 a1 = *(const float4*)&As[kk][(ty << 3) + 4];
      float a[8] = {a0.x, a0.y, a0.z, a0.w, a1.x, a1.y, a1.z, a1.w};
      float b[4] = {b4.x, b4.y, b4.z, b4.w};
#pragma unroll
      for (int i = 0; i < 8; ++i)
#pragma unroll
        for (int j = 0; j < 4; ++j)
          acc[i][j] = fmaf(a[i], b[j], acc[i][j]);
    }
    __syncthreads();
  }
  float4 bias4 = make_float4(0.f, 0.f, 0.f, 0.f);
  if (bias) bias4 = *(const float4*)(bias + col0 + (tx << 2));
#pragma unroll
  for (int i = 0; i < 8; ++i) {
    int r = row0 + (ty << 3) + i;
    if (r < M) {
      float* cp = C + (size_t)r * ldc + col0 + (tx << 2);
      float4 o;
      o.x = acc[i][0] + bias4.x;
      o.y = acc[i][1] + bias4.y;
      o.z = acc[i][2] + bias4.z;
      o.w = acc[i][3] + bias4.w;
      if (accum) {
        float4 c = *(const float4*)cp;
        o.x += c.x; o.y += c.y; o.z += c.z; o.w += c.w;
      }
      *(float4*)cp = o;
    }
  }
}

// ---------------- LayerNorm: one wave per row of 256 ----------------
__global__ __launch_bounds__(256) void ln_kernel(
    const float* __restrict__ X,
    const float* __restrict__ g, const float* __restrict__ b,
    float* __restrict__ H)
{
  int w = (blockIdx.x * blockDim.x + threadIdx.x) >> 6;
  int lane = threadIdx.x & 63;
  if (w >= NTOT) return;
  int type = (w < NS0) ? 0 : (w < OFF2 ? 1 : 2);
  float4 x = *(const float4*)(X + (size_t)w * 256 + (lane << 2));
  float s = x.x + x.y + x.z + x.w;
  float q = x.x * x.x + x.y * x.y + x.z * x.z + x.w * x.w;
#pragma unroll
  for (int off = 32; off >= 1; off >>= 1) {
    s += __shfl_xor(s, off);
    q += __shfl_xor(q, off);
  }
  float m = s * (1.f / 256.f);
  float var = q * (1.f / 256.f) - m * m;
  float rs = rsqrtf(var + 1e-5f);
  float4 gg = *(const float4*)(g + type * 256 + (lane << 2));
  float4 bb = *(const float4*)(b + type * 256 + (lane << 2));
  float4 o;
  o.x = (x.x - m) * rs * gg.x + bb.x;
  o.y = (x.y - m) * rs * gg.y + bb.y;
  o.z = (x.z - m) * rs * gg.z + bb.z;
  o.w = (x.w - m) * rs * gg.w + bb.w;
  *(float4*)(H + (size_t)w * 256 + (lane << 2)) = o;
}

// ---------------- CSR build ----------------
__global__ void csr_hist(const int* __restrict__ ei, int ne, int* __restrict__ deg) {
  int t = blockIdx.x * blockDim.x + threadIdx.x;
  if (t < ne) atomicAdd(&deg[ei[ne + t]], 1);
}

// per-block exclusive scan over 1024 elems (256 thr x 4)
__global__ __launch_bounds__(256) void scan_block(
    const int* __restrict__ in, int n, int* __restrict__ out, int* __restrict__ bsum)
{
  __shared__ int sdata[256];
  int tid = threadIdx.x;
  int base = blockIdx.x * 1024 + tid * 4;
  int v[4]; int s = 0;
#pragma unroll
  for (int j = 0; j < 4; ++j) {
    int x = (base + j < n) ? in[base + j] : 0;
    v[j] = s; s += x;
  }
  sdata[tid] = s;
  __syncthreads();
  int own = s;
  for (int off = 1; off < 256; off <<= 1) {
    int u = (tid >= off) ? sdata[tid - off] : 0;
    __syncthreads();
    sdata[tid] += u;
    __syncthreads();
  }
  int thrExcl = sdata[tid] - own;
#pragma unroll
  for (int j = 0; j < 4; ++j)
    if (base + j < n) out[base + j] = thrExcl + v[j];
  if (tid == 255) bsum[blockIdx.x] = sdata[255];
}

__global__ void scan_bsum(int* __restrict__ bsum, int nb) {
  if (threadIdx.x == 0 && blockIdx.x == 0) {
    int r = 0;
    for (int b = 0; b < nb; ++b) { int t = bsum[b]; bsum[b] = r; r += t; }
    bsum[nb] = r;
  }
}

__global__ void scan_add(int* __restrict__ out, int n, const int* __restrict__ bsum, int nb) {
  int i = blockIdx.x * blockDim.x + threadIdx.x;
  if (i < n) out[i] += bsum[i >> 10];
  else if (i == n) out[n] = bsum[nb];
}

__global__ void csr_scatter(const int* __restrict__ ei, int ne,
                            const int* __restrict__ rowptr, int* __restrict__ cur,
                            int* __restrict__ eidx) {
  int t = blockIdx.x * blockDim.x + threadIdx.x;
  if (t >= ne) return;
  int d = ei[ne + t];
  int pos = rowptr[d] + atomicAdd(&cur[d], 1);
  eidx[pos] = t;
}

// ---------------- edge scores: one wave per edge (no atomics) ----------------
__global__ __launch_bounds__(256) void edge_scores(
    const int* __restrict__ ei, int ne,
    const float* __restrict__ Q, int dst_off,
    const float* __restrict__ KR,
    const float* __restrict__ prel,
    float* __restrict__ SC, size_t sc_off)
{
  int w = (blockIdx.x * blockDim.x + threadIdx.x) >> 6;
  int lane = threadIdx.x & 63;
  if (w >= ne) return;
  int src = ei[w];
  int dst = ei[ne + w];
  float4 q4 = *(const float4*)(Q + (size_t)(dst_off + dst) * 256 + (lane << 2));
  float4 k4 = *(const float4*)(KR + (size_t)src * 256 + (lane << 2));
  float s = q4.x * k4.x + q4.y * k4.y + q4.z * k4.z + q4.w * k4.w;
  s += __shfl_xor(s, 8, 16);
  s += __shfl_xor(s, 4, 16);
  s += __shfl_xor(s, 2, 16);
  s += __shfl_xor(s, 1, 16);
  int h = lane >> 4;
  if ((lane & 15) == 0)
    SC[(sc_off + w) * 4 + h] = s * prel[h] * 0.125f;
}

// ---------------- per-node softmax over incoming edges (1 thread per node*head) ----
__global__ __launch_bounds__(256) void node_softmax(
    int n,
    const int* __restrict__ rpA, const int* __restrict__ exA, size_t scA,
    const int* __restrict__ rpB, const int* __restrict__ exB, size_t scB,
    float* __restrict__ SC)
{
  int gid = blockIdx.x * blockDim.x + threadIdx.x;
  if (gid >= n * 4) return;
  int nd = gid >> 2, h = gid & 3;
  int a0 = rpA[nd], a1 = rpA[nd + 1];
  int b0 = 0, b1 = 0;
  if (rpB) { b0 = rpB[nd]; b1 = rpB[nd + 1]; }
  if (a1 == a0 && b1 == b0) return;
  float m = -INFINITY;
  for (int i = a0; i < a1; ++i) m = fmaxf(m, SC[(scA + exA[i]) * 4 + h]);
  for (int i = b0; i < b1; ++i) m = fmaxf(m, SC[(scB + exB[i]) * 4 + h]);
  float z = 0.f;
  for (int i = a0; i < a1; ++i) {
    size_t p = (scA + exA[i]) * 4 + h;
    float e = expf(SC[p] - m); SC[p] = e; z += e;
  }
  for (int i = b0; i < b1; ++i) {
    size_t p = (scB + exB[i]) * 4 + h;
    float e = expf(SC[p] - m); SC[p] = e; z += e;
  }
  float inv = 1.f / (z + 1e-16f);
  for (int i = a0; i < a1; ++i) SC[(scA + exA[i]) * 4 + h] *= inv;
  for (int i = b0; i < b1; ++i) SC[(scB + exB[i]) * 4 + h] *= inv;
}

// ---------------- per-node aggregation (1 wave per node), GELU fused ----------------
__global__ __launch_bounds__(256) void node_aggr(
    int n, int dst_off,
    const int* __restrict__ rpA, const int* __restrict__ exA, const int* __restrict__ srcA,
    size_t scA, const float* __restrict__ VA,
    const int* __restrict__ rpB, const int* __restrict__ exB, const int* __restrict__ srcB,
    size_t scB, const float* __restrict__ VB,
    const float* __restrict__ SC, float* __restrict__ AGG)
{
  int wid = (blockIdx.x * blockDim.x + threadIdx.x) >> 6;
  int lane = threadIdx.x & 63;
  if (wid >= n) return;
  int h = lane >> 4;
  float4 acc = make_float4(0.f, 0.f, 0.f, 0.f);
  int a0 = rpA[wid], a1 = rpA[wid + 1];
  for (int i = a0; i < a1; ++i) {
    int ee = exA[i];
    float at = SC[(scA + ee) * 4 + h];
    float4 v4 = *(const float4*)(VA + (size_t)srcA[ee] * 256 + (lane << 2));
    acc.x = fmaf(at, v4.x, acc.x);
    acc.y = fmaf(at, v4.y, acc.y);
    acc.z = fmaf(at, v4.z, acc.z);
    acc.w = fmaf(at, v4.w, acc.w);
  }
  if (rpB) {
    int b0 = rpB[wid], b1 = rpB[wid + 1];
    for (int i = b0; i < b1; ++i) {
      int ee = exB[i];
      float at = SC[(scB + ee) * 4 + h];
      float4 v4 = *(const float4*)(VB + (size_t)srcB[ee] * 256 + (lane << 2));
      acc.x = fmaf(at, v4.x, acc.x);
      acc.y = fmaf(at, v4.y, acc.y);
      acc.z = fmaf(at, v4.z, acc.z);
      acc.w = fmaf(at, v4.w, acc.w);
    }
  }
  float4 o;
  o.x = gelu_f(acc.x); o.y = gelu_f(acc.y); o.z = gelu_f(acc.z); o.w = gelu_f(acc.w);
  *(float4*)(AGG + (size_t)(dst_off + wid) * 256 + (lane << 2)) = o;
}

// Xcur = alpha*TMP + (1-alpha)*Hb
__global__ __launch_bounds__(256) void skip_store(
    const float* __restrict__ TMP, const float* __restrict__ Hb,
    const float* __restrict__ skipv, float* __restrict__ Xcur)
{
  int t = blockIdx.x * blockDim.x + threadIdx.x;
  if (t >= NTOT * 64) return;
  int w = t >> 6;
  int f4 = (t & 63) << 2;
  int type = (w < NS0) ? 0 : (w < OFF2 ? 1 : 2);
  float al = 1.f / (1.f + expf(-skipv[type]));
  float4 a = *(const float4*)(TMP + (size_t)w * 256 + f4);
  float4 h = *(const float4*)(Hb + (size_t)w * 256 + f4);
  float4 o;
  o.x = al * a.x + (1.f - al) * h.x;
  o.y = al * a.y + (1.f - al) * h.y;
  o.z = al * a.z + (1.f - al) * h.z;
  o.w = al * a.w + (1.f - al) * h.w;
  *(float4*)(Xcur + (size_t)w * 256 + f4) = o;
}

__global__ void fill_kernel(float* __restrict__ p, float v, int n) {
  int i = blockIdx.x * blockDim.x + threadIdx.x;
  if (i < n) p[i] = v;
}

// ---------------- pooling ----------------
__global__ __launch_bounds__(256) void gate_score(
    const float* __restrict__ JK, const float* __restrict__ Wg, const float* __restrict__ bg,
    const int* __restrict__ batch, float* __restrict__ GS, float* __restrict__ GMX, int n)
{
  int w = (blockIdx.x * blockDim.x + threadIdx.x) >> 6;
  int lane = threadIdx.x & 63;
  if (w >= n) return;
  float4 x = *(const float4*)(JK + (size_t)w * 256 + (lane << 2));
  float4 g4 = *(const float4*)(Wg + (lane << 2));
  float s = x.x * g4.x + x.y * g4.y + x.z * g4.z + x.w * g4.w;
#pragma unroll
  for (int off = 32; off >= 1; off >>= 1) s += __shfl_xor(s, off);
  if (lane == 0) {
    float v = s + bg[0];
    GS[w] = v;
    atomicMaxF(&GMX[batch[w]], v);
  }
}

__global__ __launch_bounds__(256) void gate_expz(
    float* __restrict__ GS, const float* __restrict__ GMX, float* __restrict__ GZ,
    const int* __restrict__ batch, int n)
{
  int w = blockIdx.x * blockDim.x + threadIdx.x;
  if (w >= n) return;
  int b = batch[w];
  float e = expf(GS[w] - GMX[b]);
  GS[w] = e;
  atomicAdd(&GZ[b], e);
}

__global__ __launch_bounds__(256) void pool_kernel(
    const float* __restrict__ JK, const float* __restrict__ GS, const float* __restrict__ GZ,
    const int* __restrict__ batch, float* __restrict__ O784, int colOff, int n)
{
  int w = (blockIdx.x * blockDim.x + threadIdx.x) >> 6;
  int lane = threadIdx.x & 63;
  if (w >= n) return;
  int b = batch[w];
  float wt = GS[w] / (GZ[b] + 1e-16f);
  float4 x = *(const float4*)(JK + (size_t)w * 256 + (lane << 2));
  float* dp = O784 + (size_t)b * 784 + colOff + (lane << 2);
  atomicAdd(dp + 0, x.x * wt);
  atomicAdd(dp + 1, x.y * wt);
  atomicAdd(dp + 2, x.z * wt);
  atomicAdd(dp + 3, x.w * wt);
}

__global__ void hy_kernel(
    const float* __restrict__ y, const float* __restrict__ W1, const float* __restrict__ b1,
    const float* __restrict__ W2, const float* __restrict__ b2, float* __restrict__ O784)
{
  int r = threadIdx.x;
  if (r >= 64) return;
  float yv = y[r];
  float h1[16];
#pragma unroll
  for (int j = 0; j < 16; ++j) {
    float v = yv * W1[j] + b1[j];
    h1[j] = v > 0.f ? v : 0.2f * v;
  }
#pragma unroll
  for (int c = 0; c < 16; ++c) {
    float s = b2[c];
#pragma unroll
    for (int j = 0; j < 16; ++j) s += h1[j] * W2[j * 16 + c];
    O784[(size_t)r * 784 + 768 + c] = s;
  }
}

__global__ void dense_small(
    const float* __restrict__ A, int K, int N,
    const float* __restrict__ W, const float* __restrict__ b, float* __restrict__ C)
{
  int r = blockIdx.x;
  int c = threadIdx.x;
  if (c >= N) return;
  float s = b[c];
  for (int k = 0; k < K; ++k) s += A[(size_t)r * K + k] * W[(size_t)k * N + c];
  C[(size_t)r * N + c] = s;
}

__global__ void bn_gelu(
    const float* __restrict__ in, const float* __restrict__ g, const float* __restrict__ be,
    float* __restrict__ out, int C)
{
  int c = threadIdx.x;
  if (c >= C) return;
  float s = 0.f, sq = 0.f;
  for (int r = 0; r < 64; ++r) {
    float v = in[r * C + c];
    s += v;
    sq += v * v;
  }
  float m = s * (1.f / 64.f);
  float var = sq * (1.f / 64.f) - m * m;
  float rs = rsqrtf(var + 1e-5f);
  for (int r = 0; r < 64; ++r) {
    float v = (in[r * C + c] - m) * rs * g[c] + be[c];
    out[r * C + c] = gelu_f(v);
  }
}

extern "C" void kernel_launch(void* const* d_in, const int* in_sizes, int n_in,
                              void* d_out, int out_size, void* d_ws, size_t ws_size,
                              hipStream_t stream)
{
  const float* x_in[3] = {(const float*)d_in[0], (const float*)d_in[1], (const float*)d_in[2]};
  const float* y_base = (const float*)d_in[3];
  const float* W_in = (const float*)d_in[4];
  const float* b_in = (const float*)d_in[5];
  const float* ln_g = (const float*)d_in[6];
  const float* ln_b = (const float*)d_in[7];
  const float* W_kqv = (const float*)d_in[8];
  const float* b_kqv = (const float*)d_in[9];
  const float* W_krel = (const float*)d_in[10];
  const float* W_vrel = (const float*)d_in[11];
  const float* p_rel = (const float*)d_in[12];
  const float* W_out = (const float*)d_in[13];
  const float* b_out = (const float*)d_in[14];
  const float* skipv = (const float*)d_in[15];
  const float* W_jk = (const float*)d_in[16];
  const float* b_jk = (const float*)d_in[17];
  const float* W_gate = (const float*)d_in[18];
  const float* b_gate = (const float*)d_in[19];
  const float* W_y1 = (const float*)d_in[20];
  const float* b_y1 = (const float*)d_in[21];
  const float* W_y2 = (const float*)d_in[22];
  const float* b_y2 = (const float*)d_in[23];
  const float* Wg1 = (const float*)d_in[24];
  const float* bg1 = (const float*)d_in[25];
  const float* g1 = (const float*)d_in[26];
  const float* beta1 = (const float*)d_in[27];
  const float* Wg2 = (const float*)d_in[28];
  const float* bg2 = (const float*)d_in[29];
  const float* g2 = (const float*)d_in[30];
  const float* beta2 = (const float*)d_in[31];
  const float* Wg3 = (const float*)d_in[32];
  const float* bg3 = (const float*)d_in[33];
  const int* eis[4] = {(const int*)d_in[34], (const int*)d_in[35], (const int*)d_in[36], (const int*)d_in[37]};
  const int* batchp[3] = {(const int*)d_in[38], (const int*)d_in[39], (const int*)d_in[40]};

  const int NSs[3] = {NS0, NS1, NS2};
  const int offs[3] = {0, OFF1, OFF2};
  const int NEs[4] = {320000, 320000, 160000, 160000};
  const int stt[4] = {0, 1, 0, 2};
  const int dtt[4] = {1, 0, 2, 0};
  const size_t scoff[4] = {0, 320000, 640000, 800000};
  const size_t vroff[4] = {0, 80000, 140000, 220000};  // rows in VR (by src type count)
  const int ndst[4] = {60000, 80000, 30000, 80000};    // dst node count per edge type

  float* ws = nullptr;
  if (hipGetSymbolAddress((void**)&ws, HIP_SYMBOL(g_ws)) != hipSuccess || !ws) return;

  const size_t NODE = (size_t)NTOT * 256;
  size_t o = 0;
  float* Xcur = ws + o;  o += NODE;
  float* Hb = ws + o;    o += NODE;
  float* QA = ws + o;    o += NODE;            // q, then AGG
  float* KV = ws + o;    o += NODE;            // k, then v, then W_out output
  float* JKacc = ws + o; o += NODE;
  float* KR = ws + o;    o += (size_t)80000 * 256;
  float* VR = ws + o;    o += (size_t)250000 * 256;  // all 4 edge types
  float* SC = ws + o;    o += (size_t)960000 * 4;
  float* GS = ws + o;    o += (size_t)NTOT;
  float* GMX = ws + o;   o += 192;
  float* GZ = ws + o;    o += 192;
  float* O784 = ws + o;  o += (size_t)64 * 784;
  float* BN1 = ws + o;   o += (size_t)64 * 256;
  float* T1 = ws + o;    o += (size_t)64 * 256;
  float* BN2 = ws + o;   o += (size_t)64 * 128;
  float* T2 = ws + o;    o += (size_t)64 * 128;
  // int region
  int* ib = (int*)(ws + o);
  size_t io = 0;
  int* rp[4]; int* ex[4]; int* degc[4];
  for (int e = 0; e < 4; ++e) { rp[e] = ib + io; io += ndst[e] + 1; }
  for (int e = 0; e < 4; ++e) { ex[e] = ib + io; io += NEs[e]; }
  for (int e = 0; e < 4; ++e) { degc[e] = ib + io; io += ndst[e]; }
  int* bsum = ib + io; io += 256;

  auto gemm = [&](const float* A, int lda, const float* W, int ldw, const float* bias,
                  float* C, int ldc, int M, int N, int K, int accum) {
    dim3 g((M + 127) / 128, N / 64);
    gemm128<<<g, 256, 0, stream>>>(A, lda, W, ldw, bias, C, ldc, M, K, accum);
  };

  // ---- build CSR per edge type (edges static across layers) ----
  for (int e = 0; e < 4; ++e) {
    int n = ndst[e], ne = NEs[e];
    int nb = (n + 1023) / 1024;
    hipMemsetAsync(degc[e], 0, n * sizeof(int), stream);
    csr_hist<<<(ne + 255) / 256, 256, 0, stream>>>(eis[e], ne, degc[e]);
    scan_block<<<nb, 256, 0, stream>>>(degc[e], n, rp[e], bsum);
    scan_bsum<<<1, 1, 0, stream>>>(bsum, nb);
    scan_add<<<(n + 256) / 256, 256, 0, stream>>>(rp[e], n, bsum, nb);
    hipMemsetAsync(degc[e], 0, n * sizeof(int), stream);
    csr_scatter<<<(ne + 255) / 256, 256, 0, stream>>>(eis[e], ne, rp[e], degc[e], ex[e]);
  }

  // input projection -> Xcur
  for (int i = 0; i < 3; ++i)
    gemm(x_in[i], 128, W_in + (size_t)i * 128 * 256, 256, b_in + i * 256,
         Xcur + (size_t)offs[i] * 256, 256, NSs[i], 256, 128, 0);

  for (int l = 0; l < 4; ++l) {
    ln_kernel<<<(NTOT * 64 + 255) / 256, 256, 0, stream>>>(
        Xcur, ln_g + (size_t)l * 3 * 256, ln_b + (size_t)l * 3 * 256, Hb);

    // k -> KV, q -> QA
    for (int i = 0; i < 3; ++i) {
      const float* Wb = W_kqv + ((size_t)l * 3 + i) * 256 * 768;
      const float* bb = b_kqv + ((size_t)l * 3 + i) * 768;
      gemm(Hb + (size_t)offs[i] * 256, 256, Wb, 768, bb,
           KV + (size_t)offs[i] * 256, 256, NSs[i], 256, 256, 0);          // k
      gemm(Hb + (size_t)offs[i] * 256, 256, Wb + 256, 768, bb + 256,
           QA + (size_t)offs[i] * 256, 256, NSs[i], 256, 256, 0);          // q
    }

    // scores per edge type
    for (int e = 0; e < 4; ++e) {
      gemm(KV + (size_t)offs[stt[e]] * 256, 256,
           W_krel + ((size_t)l * 4 + e) * 256 * 256, 256, nullptr,
           KR, 256, NSs[stt[e]], 256, 256, 0);
      edge_scores<<<(NEs[e] * 64 + 255) / 256, 256, 0, stream>>>(
          eis[e], NEs[e], QA, offs[dtt[e]], KR, p_rel + ((size_t)l * 4 + e) * 4, SC, scoff[e]);
    }

    // per-node softmax: type0 <- e1+e3, type1 <- e0, type2 <- e2
    node_softmax<<<(NS0 * 4 + 255) / 256, 256, 0, stream>>>(
        NS0, rp[1], ex[1], scoff[1], rp[3], ex[3], scoff[3], SC);
    node_softmax<<<(NS1 * 4 + 255) / 256, 256, 0, stream>>>(
        NS1, rp[0], ex[0], scoff[0], nullptr, nullptr, 0, SC);
    node_softmax<<<(NS2 * 4 + 255) / 256, 256, 0, stream>>>(
        NS2, rp[2], ex[2], scoff[2], nullptr, nullptr, 0, SC);

    // v -> KV (k dead after krel GEMMs)
    for (int i = 0; i < 3; ++i) {
      const float* Wb = W_kqv + ((size_t)l * 3 + i) * 256 * 768;
      const float* bb = b_kqv + ((size_t)l * 3 + i) * 768;
      gemm(Hb + (size_t)offs[i] * 256, 256, Wb + 512, 768, bb + 512,
           KV + (size_t)offs[i] * 256, 256, NSs[i], 256, 256, 0);          // v
    }
    // vr per edge type -> VR
    for (int e = 0; e < 4; ++e)
      gemm(KV + (size_t)offs[stt[e]] * 256, 256,
           W_vrel + ((size_t)l * 4 + e) * 256 * 256, 256, nullptr,
           VR + vroff[e] * 256, 256, NSs[stt[e]], 256, 256, 0);

    // per-node aggregation (writes QA as AGG; GELU fused)
    node_aggr<<<(NS0 + 3) / 4, 256, 0, stream>>>(
        NS0, 0,
        rp[1], ex[1], eis[1], scoff[1], VR + vroff[1] * 256,
        rp[3], ex[3], eis[3], scoff[3], VR + vroff[3] * 256,
        SC, QA);
    node_aggr<<<(NS1 + 3) / 4, 256, 0, stream>>>(
        NS1, OFF1,
        rp[0], ex[0], eis[0], scoff[0], VR + vroff[0] * 256,
        nullptr, nullptr, nullptr, 0, nullptr,
        SC, QA);
    node_aggr<<<(NS2 + 3) / 4, 256, 0, stream>>>(
        NS2, OFF2,
        rp[2], ex[2], eis[2], scoff[2], VR + vroff[2] * 256,
        nullptr, nullptr, nullptr, 0, nullptr,
        SC, QA);

    // W_out -> KV (v dead)
    for (int i = 0; i < 3; ++i)
      gemm(QA + (size_t)offs[i] * 256, 256, W_out + ((size_t)l * 3 + i) * 256 * 256, 256,
           b_out + ((size_t)l * 3 + i) * 256, KV + (size_t)offs[i] * 256, 256, NSs[i], 256, 256, 0);
    // skip -> Xcur
    skip_store<<<(NTOT * 64 + 255) / 256, 256, 0, stream>>>(KV, Hb, skipv + l * 3, Xcur);

    // JKacc (+)= Xcur @ W_jk[l-slice]
    for (int i = 0; i < 3; ++i)
      gemm(Xcur + (size_t)offs[i] * 256, 256,
           W_jk + (size_t)i * 1024 * 256 + (size_t)l * 256 * 256, 256,
           (l == 0) ? (b_jk + i * 256) : nullptr,
           JKacc + (size_t)offs[i] * 256, 256, NSs[i], 256, 256, (l == 0) ? 0 : 1);
  }

  // gated pooling over JKacc
  hipMemsetAsync(GZ, 0, 192 * sizeof(float), stream);
  hipMemsetAsync(O784, 0, (size_t)64 * 784 * sizeof(float), stream);
  fill_kernel<<<1, 192, 0, stream>>>(GMX, -INFINITY, 192);
  for (int i = 0; i < 3; ++i)
    gate_score<<<(NSs[i] * 64 + 255) / 256, 256, 0, stream>>>(
        JKacc + (size_t)offs[i] * 256, W_gate + i * 256, b_gate + i, batchp[i],
        GS + offs[i], GMX + i * 64, NSs[i]);
  for (int i = 0; i < 3; ++i)
    gate_expz<<<(NSs[i] + 255) / 256, 256, 0, stream>>>(
        GS + offs[i], GMX + i * 64, GZ + i * 64, batchp[i], NSs[i]);
  for (int i = 0; i < 3; ++i)
    pool_kernel<<<(NSs[i] * 64 + 255) / 256, 256, 0, stream>>>(
        JKacc + (size_t)offs[i] * 256, GS + offs[i], GZ + i * 64, batchp[i], O784, i * 256, NSs[i]);

  hy_kernel<<<1, 64, 0, stream>>>(y_base, W_y1, b_y1, W_y2, b_y2, O784);

  // head MLP
  dense_small<<<64, 256, 0, stream>>>(O784, 784, 256, Wg1, bg1, BN1);
  bn_gelu<<<1, 256, 0, stream>>>(BN1, g1, beta1, T1, 256);
  dense_small<<<64, 128, 0, stream>>>(T1, 256, 128, Wg2, bg2, BN2);
  bn_gelu<<<1, 128, 0, stream>>>(BN2, g2, beta2, T2, 128);
  dense_small<<<64, 1, 0, stream>>>(T2, 128, 1, Wg3, bg3, (float*)d_out);
}

// Round 5
// 12448.643 us; speedup vs baseline: 2.5865x; 1.5888x over previous
//
#include <hip/hip_runtime.h>
#include <math.h>

#define NS0 80000
#define NS1 60000
#define NS2 30000
#define NTOT 170000
#define OFF1 80000
#define OFF2 140000

// bulk scratch as device global (harness ws_size too small; allocated at module load)
__device__ float g_ws[340000000];  // ~1.36 GB

typedef __attribute__((ext_vector_type(8))) short bf16x8;
typedef __attribute__((ext_vector_type(4))) float f32x4;

__device__ inline float gelu_f(float x) {
  float x3 = x * x * x;
  return 0.5f * x * (1.0f + tanhf(0.7978845608028654f * (x + 0.044715f * x3)));
}
__device__ inline ushort f2bf(float f) {
  unsigned u = __float_as_uint(f);
  unsigned r = (u + 0x7FFFu + ((u >> 16) & 1u)) >> 16;
  return (ushort)r;
}
__device__ inline float bf2f(ushort u) { return __uint_as_float((unsigned)u << 16); }
__device__ inline unsigned fkey(float f) {
  unsigned u = __float_as_uint(f);
  return (u & 0x80000000u) ? ~u : (u | 0x80000000u);
}
__device__ inline float funkey(unsigned k) {
  return __uint_as_float((k & 0x80000000u) ? (k & 0x7FFFFFFFu) : ~k);
}

// ---------------- bf16 MFMA GEMM: C[M x 256] = A_bf16[M x K] * (BT_bf16[256 x K])^T ----
// 128x128 tile, 4 waves (2x2 of 64x64), BK=32, global_load_lds staging (m97 structure).
__global__ __launch_bounds__(256) void gemm_mfma(
    const ushort* __restrict__ A, int lda,
    const ushort* __restrict__ BT, int ldb,
    const float* __restrict__ bias,
    float* __restrict__ Cf, ushort* __restrict__ Cb,
    int M, int K, int accum)
{
  __shared__ __align__(16) ushort Asl[128 * 32];
  __shared__ __align__(16) ushort Bsl[128 * 32];
  const int tid = threadIdx.x;
  const int w = tid >> 6, l = tid & 63;
  const int wr = (w >> 1) * 64, wc = (w & 1) * 64;
  const int row0 = blockIdx.x * 128;
  const int col0 = blockIdx.y * 128;
  const int lr = l >> 2;         // staging: row within 16-row chunk
  const int lk = (l & 3) * 8;    // staging: k offset (8 bf16 = 16B)
  const int fr = l & 15;         // fragment row (A) / col (B)
  const int fk = (l >> 4) * 8;   // fragment k offset

  f32x4 acc[4][4];
#pragma unroll
  for (int i = 0; i < 4; ++i)
#pragma unroll
    for (int j = 0; j < 4; ++j) acc[i][j] = (f32x4){0.f, 0.f, 0.f, 0.f};

  for (int k0 = 0; k0 < K; k0 += 32) {
    __syncthreads();
#pragma unroll
    for (int ci = 0; ci < 2; ++ci) {
      int chunk = w * 2 + ci;
      const ushort* ga = A + (size_t)(row0 + chunk * 16 + lr) * lda + k0 + lk;
      __builtin_amdgcn_global_load_lds(
          (const __attribute__((address_space(1))) void*)ga,
          (__attribute__((address_space(3))) void*)&Asl[chunk * 512], 16, 0, 0);
      const ushort* gb = BT + (size_t)(col0 + chunk * 16 + lr) * ldb + k0 + lk;
      __builtin_amdgcn_global_load_lds(
          (const __attribute__((address_space(1))) void*)gb,
          (__attribute__((address_space(3))) void*)&Bsl[chunk * 512], 16, 0, 0);
    }
    __syncthreads();
    bf16x8 af[4], bfr[4];
#pragma unroll
    for (int i = 0; i < 4; ++i)
      af[i] = *(const bf16x8*)&Asl[(wr + i * 16 + fr) * 32 + fk];
#pragma unroll
    for (int j = 0; j < 4; ++j)
      bfr[j] = *(const bf16x8*)&Bsl[(wc + j * 16 + fr) * 32 + fk];
#pragma unroll
    for (int i = 0; i < 4; ++i)
#pragma unroll
      for (int j = 0; j < 4; ++j)
        acc[i][j] = __builtin_amdgcn_mfma_f32_16x16x32_bf16(af[i], bfr[j], acc[i][j], 0, 0, 0);
  }

#pragma unroll
  for (int j = 0; j < 4; ++j) {
    int col = col0 + wc + j * 16 + fr;
    float bv = bias ? bias[col] : 0.f;
#pragma unroll
    for (int i = 0; i < 4; ++i) {
      int rbase = row0 + wr + i * 16 + (l >> 4) * 4;
#pragma unroll
      for (int r = 0; r < 4; ++r) {
        int row = rbase + r;
        if (row < M) {
          float v = acc[i][j][r] + bv;
          size_t idx = (size_t)row * 256 + col;
          if (accum) v += Cf[idx];
          if (Cf) Cf[idx] = v;
          if (Cb) Cb[idx] = f2bf(v);
        }
      }
    }
  }
}

// transpose f32 [K][N] -> bf16 [N][K], batched over blockIdx.z
__global__ __launch_bounds__(256) void wtrans(
    const float* __restrict__ src, ushort* __restrict__ dst, int K, int N)
{
  __shared__ float t[32][33];
  size_t zo = (size_t)blockIdx.z * K * N;
  int kb = blockIdx.x * 32, nb = blockIdx.y * 32;
  int tx = threadIdx.x & 31, ty = threadIdx.x >> 5;
#pragma unroll
  for (int r = 0; r < 32; r += 8) {
    int k = kb + ty + r, n = nb + tx;
    if (k < K && n < N) t[ty + r][tx] = src[zo + (size_t)k * N + n];
  }
  __syncthreads();
#pragma unroll
  for (int r = 0; r < 32; r += 8) {
    int n = nb + ty + r, k = kb + tx;
    if (n < N && k < K) dst[zo + (size_t)n * K + k] = f2bf(t[tx][ty + r]);
  }
}

__global__ void conv_bf16(const float* __restrict__ in, ushort* __restrict__ out, int n4) {
  int i = blockIdx.x * blockDim.x + threadIdx.x;
  if (i >= n4) return;
  float4 v = *(const float4*)(in + (size_t)i * 4);
  ushort4 o;
  o.x = f2bf(v.x); o.y = f2bf(v.y); o.z = f2bf(v.z); o.w = f2bf(v.w);
  *(ushort4*)(out + (size_t)i * 4) = o;
}

// ---------------- LayerNorm: one wave per row; writes f32 + bf16 ----------------
__global__ __launch_bounds__(256) void ln_kernel(
    const float* __restrict__ X,
    const float* __restrict__ g, const float* __restrict__ b,
    float* __restrict__ H, ushort* __restrict__ Hbf)
{
  int w = (blockIdx.x * blockDim.x + threadIdx.x) >> 6;
  int lane = threadIdx.x & 63;
  if (w >= NTOT) return;
  int type = (w < NS0) ? 0 : (w < OFF2 ? 1 : 2);
  float4 x = *(const float4*)(X + (size_t)w * 256 + (lane << 2));
  float s = x.x + x.y + x.z + x.w;
  float q = x.x * x.x + x.y * x.y + x.z * x.z + x.w * x.w;
#pragma unroll
  for (int off = 32; off >= 1; off >>= 1) {
    s += __shfl_xor(s, off);
    q += __shfl_xor(q, off);
  }
  float m = s * (1.f / 256.f);
  float var = q * (1.f / 256.f) - m * m;
  float rs = rsqrtf(var + 1e-5f);
  float4 gg = *(const float4*)(g + type * 256 + (lane << 2));
  float4 bb = *(const float4*)(b + type * 256 + (lane << 2));
  float4 o;
  o.x = (x.x - m) * rs * gg.x + bb.x;
  o.y = (x.y - m) * rs * gg.y + bb.y;
  o.z = (x.z - m) * rs * gg.z + bb.z;
  o.w = (x.w - m) * rs * gg.w + bb.w;
  *(float4*)(H + (size_t)w * 256 + (lane << 2)) = o;
  ushort4 ob;
  ob.x = f2bf(o.x); ob.y = f2bf(o.y); ob.z = f2bf(o.z); ob.w = f2bf(o.w);
  *(ushort4*)(Hbf + (size_t)w * 256 + (lane << 2)) = ob;
}

// ---------------- CSR build ----------------
__global__ void csr_hist(const int* __restrict__ ei, int ne, int* __restrict__ deg) {
  int t = blockIdx.x * blockDim.x + threadIdx.x;
  if (t < ne) atomicAdd(&deg[ei[ne + t]], 1);
}
__global__ __launch_bounds__(256) void scan_block(
    const int* __restrict__ in, int n, int* __restrict__ out, int* __restrict__ bsum)
{
  __shared__ int sdata[256];
  int tid = threadIdx.x;
  int base = blockIdx.x * 1024 + tid * 4;
  int v[4]; int s = 0;
#pragma unroll
  for (int j = 0; j < 4; ++j) {
    int x = (base + j < n) ? in[base + j] : 0;
    v[j] = s; s += x;
  }
  sdata[tid] = s;
  __syncthreads();
  int own = s;
  for (int off = 1; off < 256; off <<= 1) {
    int u = (tid >= off) ? sdata[tid - off] : 0;
    __syncthreads();
    sdata[tid] += u;
    __syncthreads();
  }
  int thrExcl = sdata[tid] - own;
#pragma unroll
  for (int j = 0; j < 4; ++j)
    if (base + j < n) out[base + j] = thrExcl + v[j];
  if (tid == 255) bsum[blockIdx.x] = sdata[255];
}
__global__ void scan_bsum(int* __restrict__ bsum, int nb) {
  if (threadIdx.x == 0 && blockIdx.x == 0) {
    int r = 0;
    for (int b = 0; b < nb; ++b) { int t = bsum[b]; bsum[b] = r; r += t; }
    bsum[nb] = r;
  }
}
__global__ void scan_add(int* __restrict__ out, int n, const int* __restrict__ bsum, int nb) {
  int i = blockIdx.x * blockDim.x + threadIdx.x;
  if (i < n) out[i] += bsum[i >> 10];
  else if (i == n) out[n] = bsum[nb];
}
__global__ void csr_scatter(const int* __restrict__ ei, int ne,
                            const int* __restrict__ rowptr, int* __restrict__ cur,
                            int* __restrict__ eidx) {
  int t = blockIdx.x * blockDim.x + threadIdx.x;
  if (t >= ne) return;
  int d = ei[ne + t];
  int pos = rowptr[d] + atomicAdd(&cur[d], 1);
  eidx[pos] = t;
}

// ---------------- edge scores ----------------
__global__ __launch_bounds__(256) void edge_scores(
    const int* __restrict__ ei, int ne,
    const float* __restrict__ Q, int dst_off,
    const float* __restrict__ KR,
    const float* __restrict__ prel,
    float* __restrict__ SC, size_t sc_off)
{
  int w = (blockIdx.x * blockDim.x + threadIdx.x) >> 6;
  int lane = threadIdx.x & 63;
  if (w >= ne) return;
  int src = ei[w];
  int dst = ei[ne + w];
  float4 q4 = *(const float4*)(Q + (size_t)(dst_off + dst) * 256 + (lane << 2));
  float4 k4 = *(const float4*)(KR + (size_t)src * 256 + (lane << 2));
  float s = q4.x * k4.x + q4.y * k4.y + q4.z * k4.z + q4.w * k4.w;
  s += __shfl_xor(s, 8, 16);
  s += __shfl_xor(s, 4, 16);
  s += __shfl_xor(s, 2, 16);
  s += __shfl_xor(s, 1, 16);
  int h = lane >> 4;
  if ((lane & 15) == 0)
    SC[(sc_off + w) * 4 + h] = s * prel[h] * 0.125f;
}

// ---------------- per-node softmax ----------------
__global__ __launch_bounds__(256) void node_softmax(
    int n,
    const int* __restrict__ rpA, const int* __restrict__ exA, size_t scA,
    const int* __restrict__ rpB, const int* __restrict__ exB, size_t scB,
    float* __restrict__ SC)
{
  int gid = blockIdx.x * blockDim.x + threadIdx.x;
  if (gid >= n * 4) return;
  int nd = gid >> 2, h = gid & 3;
  int a0 = rpA[nd], a1 = rpA[nd + 1];
  int b0 = 0, b1 = 0;
  if (rpB) { b0 = rpB[nd]; b1 = rpB[nd + 1]; }
  if (a1 == a0 && b1 == b0) return;
  float m = -INFINITY;
  for (int i = a0; i < a1; ++i) m = fmaxf(m, SC[(scA + exA[i]) * 4 + h]);
  for (int i = b0; i < b1; ++i) m = fmaxf(m, SC[(scB + exB[i]) * 4 + h]);
  float z = 0.f;
  for (int i = a0; i < a1; ++i) {
    size_t p = (scA + exA[i]) * 4 + h;
    float e = expf(SC[p] - m); SC[p] = e; z += e;
  }
  for (int i = b0; i < b1; ++i) {
    size_t p = (scB + exB[i]) * 4 + h;
    float e = expf(SC[p] - m); SC[p] = e; z += e;
  }
  float inv = 1.f / (z + 1e-16f);
  for (int i = a0; i < a1; ++i) SC[(scA + exA[i]) * 4 + h] *= inv;
  for (int i = b0; i < b1; ++i) SC[(scB + exB[i]) * 4 + h] *= inv;
}

// ---------------- per-node aggregation (bf16 V, bf16 out, GELU fused) ----------------
__global__ __launch_bounds__(256) void node_aggr(
    int n, int dst_off,
    const int* __restrict__ rpA, const int* __restrict__ exA, const int* __restrict__ srcA,
    size_t scA, const ushort* __restrict__ VA,
    const int* __restrict__ rpB, const int* __restrict__ exB, const int* __restrict__ srcB,
    size_t scB, const ushort* __restrict__ VB,
    const float* __restrict__ SC, ushort* __restrict__ AGGb)
{
  int wid = (blockIdx.x * blockDim.x + threadIdx.x) >> 6;
  int lane = threadIdx.x & 63;
  if (wid >= n) return;
  int h = lane >> 4;
  float ax = 0.f, ay = 0.f, az = 0.f, aw = 0.f;
  int a0 = rpA[wid], a1 = rpA[wid + 1];
  for (int i = a0; i < a1; ++i) {
    int ee = exA[i];
    float at = SC[(scA + ee) * 4 + h];
    ushort4 v4 = *(const ushort4*)(VA + (size_t)srcA[ee] * 256 + (lane << 2));
    ax = fmaf(at, bf2f(v4.x), ax);
    ay = fmaf(at, bf2f(v4.y), ay);
    az = fmaf(at, bf2f(v4.z), az);
    aw = fmaf(at, bf2f(v4.w), aw);
  }
  if (rpB) {
    int b0 = rpB[wid], b1 = rpB[wid + 1];
    for (int i = b0; i < b1; ++i) {
      int ee = exB[i];
      float at = SC[(scB + ee) * 4 + h];
      ushort4 v4 = *(const ushort4*)(VB + (size_t)srcB[ee] * 256 + (lane << 2));
      ax = fmaf(at, bf2f(v4.x), ax);
      ay = fmaf(at, bf2f(v4.y), ay);
      az = fmaf(at, bf2f(v4.z), az);
      aw = fmaf(at, bf2f(v4.w), aw);
    }
  }
  ushort4 o;
  o.x = f2bf(gelu_f(ax)); o.y = f2bf(gelu_f(ay));
  o.z = f2bf(gelu_f(az)); o.w = f2bf(gelu_f(aw));
  *(ushort4*)(AGGb + (size_t)(dst_off + wid) * 256 + (lane << 2)) = o;
}

// Xcur = alpha*TMP + (1-alpha)*Hb  (f32 + bf16 out)
__global__ __launch_bounds__(256) void skip_store(
    const float* __restrict__ TMP, const float* __restrict__ Hb,
    const float* __restrict__ skipv, float* __restrict__ Xcur, ushort* __restrict__ Xbf)
{
  int t = blockIdx.x * blockDim.x + threadIdx.x;
  if (t >= NTOT * 64) return;
  int w = t >> 6;
  int f4 = (t & 63) << 2;
  int type = (w < NS0) ? 0 : (w < OFF2 ? 1 : 2);
  float al = 1.f / (1.f + expf(-skipv[type]));
  float4 a = *(const float4*)(TMP + (size_t)w * 256 + f4);
  float4 h = *(const float4*)(Hb + (size_t)w * 256 + f4);
  float4 o;
  o.x = al * a.x + (1.f - al) * h.x;
  o.y = al * a.y + (1.f - al) * h.y;
  o.z = al * a.z + (1.f - al) * h.z;
  o.w = al * a.w + (1.f - al) * h.w;
  *(float4*)(Xcur + (size_t)w * 256 + f4) = o;
  ushort4 ob;
  ob.x = f2bf(o.x); ob.y = f2bf(o.y); ob.z = f2bf(o.z); ob.w = f2bf(o.w);
  *(ushort4*)(Xbf + (size_t)w * 256 + f4) = ob;
}

// ---------------- pooling ----------------
__global__ __launch_bounds__(256) void gate_score(
    const float* __restrict__ JK, const float* __restrict__ Wg, const float* __restrict__ bg,
    const int* __restrict__ batch, float* __restrict__ GS, unsigned* __restrict__ GMXu, int n)
{
  int w = (blockIdx.x * blockDim.x + threadIdx.x) >> 6;
  int lane = threadIdx.x & 63;
  if (w >= n) return;
  float4 x = *(const float4*)(JK + (size_t)w * 256 + (lane << 2));
  float4 g4 = *(const float4*)(Wg + (lane << 2));
  float s = x.x * g4.x + x.y * g4.y + x.z * g4.z + x.w * g4.w;
#pragma unroll
  for (int off = 32; off >= 1; off >>= 1) s += __shfl_xor(s, off);
  if (lane == 0) {
    float v = s + bg[0];
    GS[w] = v;
    atomicMax(&GMXu[batch[w]], fkey(v));   // native u32 max, no CAS loop
  }
}

__global__ __launch_bounds__(256) void gate_expz(
    float* __restrict__ GS, const unsigned* __restrict__ GMXu, float* __restrict__ GZ,
    const int* __restrict__ batch, int n)
{
  int w = blockIdx.x * blockDim.x + threadIdx.x;
  if (w >= n) return;
  int b = batch[w];
  float e = expf(GS[w] - funkey(GMXu[b]));
  GS[w] = e;
  atomicAdd(&GZ[b], e);
}

__global__ __launch_bounds__(256) void pool_kernel(
    const float* __restrict__ JK, const float* __restrict__ GS, const float* __restrict__ GZ,
    const int* __restrict__ batch, float* __restrict__ O784, int colOff, int n)
{
  int w = (blockIdx.x * blockDim.x + threadIdx.x) >> 6;
  int lane = threadIdx.x & 63;
  if (w >= n) return;
  int b = batch[w];
  float wt = GS[w] / (GZ[b] + 1e-16f);
  float4 x = *(const float4*)(JK + (size_t)w * 256 + (lane << 2));
  float* dp = O784 + (size_t)b * 784 + colOff + (lane << 2);
  atomicAdd(dp + 0, x.x * wt);
  atomicAdd(dp + 1, x.y * wt);
  atomicAdd(dp + 2, x.z * wt);
  atomicAdd(dp + 3, x.w * wt);
}

__global__ void hy_kernel(
    const float* __restrict__ y, const float* __restrict__ W1, const float* __restrict__ b1,
    const float* __restrict__ W2, const float* __restrict__ b2, float* __restrict__ O784)
{
  int r = threadIdx.x;
  if (r >= 64) return;
  float yv = y[r];
  float h1[16];
#pragma unroll
  for (int j = 0; j < 16; ++j) {
    float v = yv * W1[j] + b1[j];
    h1[j] = v > 0.f ? v : 0.2f * v;
  }
#pragma unroll
  for (int c = 0; c < 16; ++c) {
    float s = b2[c];
#pragma unroll
    for (int j = 0; j < 16; ++j) s += h1[j] * W2[j * 16 + c];
    O784[(size_t)r * 784 + 768 + c] = s;
  }
}

__global__ void dense_small(
    const float* __restrict__ A, int K, int N,
    const float* __restrict__ W, const float* __restrict__ b, float* __restrict__ C)
{
  int r = blockIdx.x;
  int c = threadIdx.x;
  if (c >= N) return;
  float s = b[c];
  for (int k = 0; k < K; ++k) s += A[(size_t)r * K + k] * W[(size_t)k * N + c];
  C[(size_t)r * N + c] = s;
}

__global__ void bn_gelu(
    const float* __restrict__ in, const float* __restrict__ g, const float* __restrict__ be,
    float* __restrict__ out, int C)
{
  int c = threadIdx.x;
  if (c >= C) return;
  float s = 0.f, sq = 0.f;
  for (int r = 0; r < 64; ++r) {
    float v = in[r * C + c];
    s += v;
    sq += v * v;
  }
  float m = s * (1.f / 64.f);
  float var = sq * (1.f / 64.f) - m * m;
  float rs = rsqrtf(var + 1e-5f);
  for (int r = 0; r < 64; ++r) {
    float v = (in[r * C + c] - m) * rs * g[c] + be[c];
    out[r * C + c] = gelu_f(v);
  }
}

extern "C" void kernel_launch(void* const* d_in, const int* in_sizes, int n_in,
                              void* d_out, int out_size, void* d_ws, size_t ws_size,
                              hipStream_t stream)
{
  const float* x_in[3] = {(const float*)d_in[0], (const float*)d_in[1], (const float*)d_in[2]};
  const float* y_base = (const float*)d_in[3];
  const float* W_in = (const float*)d_in[4];
  const float* b_in = (const float*)d_in[5];
  const float* ln_g = (const float*)d_in[6];
  const float* ln_b = (const float*)d_in[7];
  const float* W_kqv = (const float*)d_in[8];
  const float* b_kqv = (const float*)d_in[9];
  const float* W_krel = (const float*)d_in[10];
  const float* W_vrel = (const float*)d_in[11];
  const float* p_rel = (const float*)d_in[12];
  const float* W_out = (const float*)d_in[13];
  const float* b_out = (const float*)d_in[14];
  const float* skipv = (const float*)d_in[15];
  const float* W_jk = (const float*)d_in[16];
  const float* b_jk = (const float*)d_in[17];
  const float* W_gate = (const float*)d_in[18];
  const float* b_gate = (const float*)d_in[19];
  const float* W_y1 = (const float*)d_in[20];
  const float* b_y1 = (const float*)d_in[21];
  const float* W_y2 = (const float*)d_in[22];
  const float* b_y2 = (const float*)d_in[23];
  const float* Wg1 = (const float*)d_in[24];
  const float* bg1 = (const float*)d_in[25];
  const float* g1 = (const float*)d_in[26];
  const float* beta1 = (const float*)d_in[27];
  const float* Wg2 = (const float*)d_in[28];
  const float* bg2 = (const float*)d_in[29];
  const float* g2 = (const float*)d_in[30];
  const float* beta2 = (const float*)d_in[31];
  const float* Wg3 = (const float*)d_in[32];
  const float* bg3 = (const float*)d_in[33];
  const int* eis[4] = {(const int*)d_in[34], (const int*)d_in[35], (const int*)d_in[36], (const int*)d_in[37]};
  const int* batchp[3] = {(const int*)d_in[38], (const int*)d_in[39], (const int*)d_in[40]};

  const int NSs[3] = {NS0, NS1, NS2};
  const int offs[3] = {0, OFF1, OFF2};
  const int NEs[4] = {320000, 320000, 160000, 160000};
  const int stt[4] = {0, 1, 0, 2};
  const int dtt[4] = {1, 0, 2, 0};
  const size_t scoff[4] = {0, 320000, 640000, 800000};
  const size_t vroff[4] = {0, 80000, 140000, 220000};
  const int ndst[4] = {60000, 80000, 30000, 80000};

  float* ws = nullptr;
  if (hipGetSymbolAddress((void**)&ws, HIP_SYMBOL(g_ws)) != hipSuccess || !ws) return;

  const size_t NODE = (size_t)NTOT * 256;
  size_t o = 0;
  // f32 buffers
  float* Xcur = ws + o;  o += NODE;
  float* Hb = ws + o;    o += NODE;
  float* Q = ws + o;     o += NODE;            // q f32, later W_out output
  float* JKacc = ws + o; o += NODE;
  float* KR = ws + o;    o += (size_t)80000 * 256;
  float* SC = ws + o;    o += (size_t)960000 * 4;
  float* GS = ws + o;    o += (size_t)NTOT;
  float* GZ = ws + o;    o += 192;
  float* O784 = ws + o;  o += (size_t)64 * 784;
  float* BN1 = ws + o;   o += (size_t)64 * 256;
  float* T1 = ws + o;    o += (size_t)64 * 256;
  float* BN2 = ws + o;   o += (size_t)64 * 128;
  float* T2 = ws + o;    o += (size_t)64 * 128;
  unsigned* GMXu = (unsigned*)(ws + o); o += 192;
  // bf16 buffers (ushort), sized in float units (ceil /2)
  ushort* Xin_bf = (ushort*)(ws + o);  o += (size_t)NTOT * 128 / 2;
  ushort* Hb_bf = (ushort*)(ws + o);   o += NODE / 2;
  ushort* Xcur_bf = (ushort*)(ws + o); o += NODE / 2;
  ushort* Kbf = (ushort*)(ws + o);     o += NODE / 2;   // k, then v
  ushort* AGGb = (ushort*)(ws + o);    o += NODE / 2;
  ushort* VRb = (ushort*)(ws + o);     o += (size_t)250000 * 256 / 2;
  // transposed bf16 weights
  ushort* WT_in = (ushort*)(ws + o);   o += (size_t)3 * 256 * 128 / 2;
  ushort* WT_kqv = (ushort*)(ws + o);  o += (size_t)12 * 768 * 256 / 2;
  ushort* WT_krel = (ushort*)(ws + o); o += (size_t)16 * 256 * 256 / 2;
  ushort* WT_vrel = (ushort*)(ws + o); o += (size_t)16 * 256 * 256 / 2;
  ushort* WT_out = (ushort*)(ws + o);  o += (size_t)12 * 256 * 256 / 2;
  ushort* WT_jk = (ushort*)(ws + o);   o += (size_t)3 * 256 * 1024 / 2;
  // int region (keep LAST so bf16 A-operand tail over-reads stay in-bounds)
  int* ib = (int*)(ws + o);
  size_t io = 0;
  int* rp[4]; int* ex[4]; int* degc[4];
  for (int e = 0; e < 4; ++e) { rp[e] = ib + io; io += ndst[e] + 1; }
  for (int e = 0; e < 4; ++e) { ex[e] = ib + io; io += NEs[e]; }
  for (int e = 0; e < 4; ++e) { degc[e] = ib + io; io += ndst[e]; }
  int* bsum = ib + io; io += 257;

  auto gemm = [&](const ushort* A, int lda, const ushort* BT, int ldb, const float* bias,
                  float* Cf, ushort* Cb, int M, int K, int accum) {
    dim3 g((M + 127) / 128, 2);
    gemm_mfma<<<g, 256, 0, stream>>>(A, lda, BT, ldb, bias, Cf, Cb, M, K, accum);
  };

  // ---- weight transpose + bf16 convert (once per call) ----
  wtrans<<<dim3(4, 8, 3), 256, 0, stream>>>(W_in, WT_in, 128, 256);
  wtrans<<<dim3(8, 24, 12), 256, 0, stream>>>(W_kqv, WT_kqv, 256, 768);
  wtrans<<<dim3(8, 8, 16), 256, 0, stream>>>(W_krel, WT_krel, 256, 256);
  wtrans<<<dim3(8, 8, 16), 256, 0, stream>>>(W_vrel, WT_vrel, 256, 256);
  wtrans<<<dim3(8, 8, 12), 256, 0, stream>>>(W_out, WT_out, 256, 256);
  wtrans<<<dim3(32, 8, 3), 256, 0, stream>>>(W_jk, WT_jk, 1024, 256);

  // ---- input bf16 conversion ----
  for (int i = 0; i < 3; ++i) {
    int n4 = NSs[i] * 128 / 4;
    conv_bf16<<<(n4 + 255) / 256, 256, 0, stream>>>(x_in[i], Xin_bf + (size_t)offs[i] * 128, n4);
  }

  // ---- build CSR per edge type ----
  for (int e = 0; e < 4; ++e) {
    int n = ndst[e], ne = NEs[e];
    int nb = (n + 1023) / 1024;
    hipMemsetAsync(degc[e], 0, n * sizeof(int), stream);
    csr_hist<<<(ne + 255) / 256, 256, 0, stream>>>(eis[e], ne, degc[e]);
    scan_block<<<nb, 256, 0, stream>>>(degc[e], n, rp[e], bsum);
    scan_bsum<<<1, 1, 0, stream>>>(bsum, nb);
    scan_add<<<(n + 256) / 256, 256, 0, stream>>>(rp[e], n, bsum, nb);
    hipMemsetAsync(degc[e], 0, n * sizeof(int), stream);
    csr_scatter<<<(ne + 255) / 256, 256, 0, stream>>>(eis[e], ne, rp[e], degc[e], ex[e]);
  }

  // ---- input projection -> Xcur (f32) ----
  for (int i = 0; i < 3; ++i)
    gemm(Xin_bf + (size_t)offs[i] * 128, 128, WT_in + (size_t)i * 256 * 128, 128,
         b_in + i * 256, Xcur + (size_t)offs[i] * 256, nullptr, NSs[i], 128, 0);

  for (int l = 0; l < 4; ++l) {
    ln_kernel<<<(NTOT * 64 + 255) / 256, 256, 0, stream>>>(
        Xcur, ln_g + (size_t)l * 3 * 256, ln_b + (size_t)l * 3 * 256, Hb, Hb_bf);

    // k -> Kbf (bf16), q -> Q (f32)
    for (int i = 0; i < 3; ++i) {
      const ushort* WT = WT_kqv + ((size_t)l * 3 + i) * 768 * 256;
      const float* bb = b_kqv + ((size_t)l * 3 + i) * 768;
      gemm(Hb_bf + (size_t)offs[i] * 256, 256, WT, 256, bb,
           nullptr, Kbf + (size_t)offs[i] * 256, NSs[i], 256, 0);                 // k
      gemm(Hb_bf + (size_t)offs[i] * 256, 256, WT + (size_t)256 * 256, 256, bb + 256,
           Q + (size_t)offs[i] * 256, nullptr, NSs[i], 256, 0);                   // q
    }

    // scores per edge type
    for (int e = 0; e < 4; ++e) {
      gemm(Kbf + (size_t)offs[stt[e]] * 256, 256,
           WT_krel + ((size_t)l * 4 + e) * 256 * 256, 256, nullptr,
           KR, nullptr, NSs[stt[e]], 256, 0);
      edge_scores<<<(NEs[e] * 64 + 255) / 256, 256, 0, stream>>>(
          eis[e], NEs[e], Q, offs[dtt[e]], KR, p_rel + ((size_t)l * 4 + e) * 4, SC, scoff[e]);
    }

    node_softmax<<<(NS0 * 4 + 255) / 256, 256, 0, stream>>>(
        NS0, rp[1], ex[1], scoff[1], rp[3], ex[3], scoff[3], SC);
    node_softmax<<<(NS1 * 4 + 255) / 256, 256, 0, stream>>>(
        NS1, rp[0], ex[0], scoff[0], nullptr, nullptr, 0, SC);
    node_softmax<<<(NS2 * 4 + 255) / 256, 256, 0, stream>>>(
        NS2, rp[2], ex[2], scoff[2], nullptr, nullptr, 0, SC);

    // v -> Kbf (reuse; all krel GEMMs done)
    for (int i = 0; i < 3; ++i) {
      const ushort* WT = WT_kqv + ((size_t)l * 3 + i) * 768 * 256;
      const float* bb = b_kqv + ((size_t)l * 3 + i) * 768;
      gemm(Hb_bf + (size_t)offs[i] * 256, 256, WT + (size_t)512 * 256, 256, bb + 512,
           nullptr, Kbf + (size_t)offs[i] * 256, NSs[i], 256, 0);                 // v
    }
    // vr per edge type -> VRb (bf16)
    for (int e = 0; e < 4; ++e)
      gemm(Kbf + (size_t)offs[stt[e]] * 256, 256,
           WT_vrel + ((size_t)l * 4 + e) * 256 * 256, 256, nullptr,
           nullptr, VRb + vroff[e] * 256, NSs[stt[e]], 256, 0);

    // per-node aggregation -> AGGb (bf16, GELU fused)
    node_aggr<<<(NS0 + 3) / 4, 256, 0, stream>>>(
        NS0, 0,
        rp[1], ex[1], eis[1], scoff[1], VRb + vroff[1] * 256,
        rp[3], ex[3], eis[3], scoff[3], VRb + vroff[3] * 256,
        SC, AGGb);
    node_aggr<<<(NS1 + 3) / 4, 256, 0, stream>>>(
        NS1, OFF1,
        rp[0], ex[0], eis[0], scoff[0], VRb + vroff[0] * 256,
        nullptr, nullptr, nullptr, 0, nullptr,
        SC, AGGb);
    node_aggr<<<(NS2 + 3) / 4, 256, 0, stream>>>(
        NS2, OFF2,
        rp[2], ex[2], eis[2], scoff[2], VRb + vroff[2] * 256,
        nullptr, nullptr, nullptr, 0, nullptr,
        SC, AGGb);

    // W_out: AGGb -> Q (f32, reuse; q dead)
    for (int i = 0; i < 3; ++i)
      gemm(AGGb + (size_t)offs[i] * 256, 256,
           WT_out + ((size_t)l * 3 + i) * 256 * 256, 256,
           b_out + ((size_t)l * 3 + i) * 256,
           Q + (size_t)offs[i] * 256, nullptr, NSs[i], 256, 0);

    skip_store<<<(NTOT * 64 + 255) / 256, 256, 0, stream>>>(
        Q, Hb, skipv + l * 3, Xcur, Xcur_bf);

    // JKacc (+)= Xcur_bf @ W_jk[l-slice]
    for (int i = 0; i < 3; ++i)
      gemm(Xcur_bf + (size_t)offs[i] * 256, 256,
           WT_jk + (size_t)i * 256 * 1024 + (size_t)l * 256, 1024,
           (l == 0) ? (b_jk + i * 256) : nullptr,
           JKacc + (size_t)offs[i] * 256, nullptr, NSs[i], 256, (l == 0) ? 0 : 1);
  }

  // ---- gated pooling ----
  hipMemsetAsync(GZ, 0, 192 * sizeof(float), stream);
  hipMemsetAsync(GMXu, 0, 192 * sizeof(unsigned), stream);  // 0 == encoded -inf
  hipMemsetAsync(O784, 0, (size_t)64 * 784 * sizeof(float), stream);
  for (int i = 0; i < 3; ++i)
    gate_score<<<(NSs[i] * 64 + 255) / 256, 256, 0, stream>>>(
        JKacc + (size_t)offs[i] * 256, W_gate + i * 256, b_gate + i, batchp[i],
        GS + offs[i], GMXu + i * 64, NSs[i]);
  for (int i = 0; i < 3; ++i)
    gate_expz<<<(NSs[i] + 255) / 256, 256, 0, stream>>>(
        GS + offs[i], GMXu + i * 64, GZ + i * 64, batchp[i], NSs[i]);
  for (int i = 0; i < 3; ++i)
    pool_kernel<<<(NSs[i] * 64 + 255) / 256, 256, 0, stream>>>(
        JKacc + (size_t)offs[i] * 256, GS + offs[i], GZ + i * 64, batchp[i], O784, i * 256, NSs[i]);

  hy_kernel<<<1, 64, 0, stream>>>(y_base, W_y1, b_y1, W_y2, b_y2, O784);

  // head MLP
  dense_small<<<64, 256, 0, stream>>>(O784, 784, 256, Wg1, bg1, BN1);
  bn_gelu<<<1, 256, 0, stream>>>(BN1, g1, beta1, T1, 256);
  dense_small<<<64, 128, 0, stream>>>(T1, 256, 128, Wg2, bg2, BN2);
  bn_gelu<<<1, 128, 0, stream>>>(BN2, g2, beta2, T2, 128);
  dense_small<<<64, 1, 0, stream>>>(T2, 128, 1, Wg3, bg3, (float*)d_out);
}

// Round 6
// 9457.890 us; speedup vs baseline: 3.4044x; 1.3162x over previous
//
#include <hip/hip_runtime.h>
#include <math.h>

#define NS0 80000
#define NS1 60000
#define NS2 30000
#define NTOT 170000
#define OFF1 80000
#define OFF2 140000

// bulk scratch as device global (harness ws_size too small; allocated at module load)
__device__ float g_ws[372000000];  // ~1.49 GB

typedef __attribute__((ext_vector_type(8))) short bf16x8;
typedef __attribute__((ext_vector_type(4))) float f32x4;

__device__ inline float gelu_f(float x) {
  float x3 = x * x * x;
  return 0.5f * x * (1.0f + tanhf(0.7978845608028654f * (x + 0.044715f * x3)));
}
__device__ inline ushort f2bf(float f) {
  unsigned u = __float_as_uint(f);
  unsigned r = (u + 0x7FFFu + ((u >> 16) & 1u)) >> 16;
  return (ushort)r;
}
__device__ inline float bf2f(ushort u) { return __uint_as_float((unsigned)u << 16); }

// ---- bf16 MFMA GEMM: C[M x N] = A_bf16[M x K] * (BT_bf16[N x K])^T, N = 128*gridDim.y ----
// 128x128 tile, 4 waves, BK=32, global_load_lds staging (m97 structure).
__global__ __launch_bounds__(256) void gemm_mfma(
    const ushort* __restrict__ A, int lda,
    const ushort* __restrict__ BT, int ldb,
    const float* __restrict__ bias,
    float* __restrict__ Cf, ushort* __restrict__ Cb, int ldc,
    int M, int K, int accum)
{
  __shared__ __align__(16) ushort Asl[128 * 32];
  __shared__ __align__(16) ushort Bsl[128 * 32];
  const int tid = threadIdx.x;
  const int w = tid >> 6, l = tid & 63;
  const int wr = (w >> 1) * 64, wc = (w & 1) * 64;
  const int row0 = blockIdx.x * 128;
  const int col0 = blockIdx.y * 128;
  const int lr = l >> 2;
  const int lk = (l & 3) * 8;
  const int fr = l & 15;
  const int fk = (l >> 4) * 8;

  f32x4 acc[4][4];
#pragma unroll
  for (int i = 0; i < 4; ++i)
#pragma unroll
    for (int j = 0; j < 4; ++j) acc[i][j] = (f32x4){0.f, 0.f, 0.f, 0.f};

  for (int k0 = 0; k0 < K; k0 += 32) {
    __syncthreads();
#pragma unroll
    for (int ci = 0; ci < 2; ++ci) {
      int chunk = w * 2 + ci;
      const ushort* ga = A + (size_t)(row0 + chunk * 16 + lr) * lda + k0 + lk;
      __builtin_amdgcn_global_load_lds(
          (const __attribute__((address_space(1))) void*)ga,
          (__attribute__((address_space(3))) void*)&Asl[chunk * 512], 16, 0, 0);
      const ushort* gb = BT + (size_t)(col0 + chunk * 16 + lr) * ldb + k0 + lk;
      __builtin_amdgcn_global_load_lds(
          (const __attribute__((address_space(1))) void*)gb,
          (__attribute__((address_space(3))) void*)&Bsl[chunk * 512], 16, 0, 0);
    }
    __syncthreads();
    bf16x8 af[4], bfr[4];
#pragma unroll
    for (int i = 0; i < 4; ++i)
      af[i] = *(const bf16x8*)&Asl[(wr + i * 16 + fr) * 32 + fk];
#pragma unroll
    for (int j = 0; j < 4; ++j)
      bfr[j] = *(const bf16x8*)&Bsl[(wc + j * 16 + fr) * 32 + fk];
#pragma unroll
    for (int i = 0; i < 4; ++i)
#pragma unroll
      for (int j = 0; j < 4; ++j)
        acc[i][j] = __builtin_amdgcn_mfma_f32_16x16x32_bf16(af[i], bfr[j], acc[i][j], 0, 0, 0);
  }

#pragma unroll
  for (int j = 0; j < 4; ++j) {
    int col = col0 + wc + j * 16 + fr;
    float bv = bias ? bias[col] : 0.f;
#pragma unroll
    for (int i = 0; i < 4; ++i) {
      int rbase = row0 + wr + i * 16 + (l >> 4) * 4;
#pragma unroll
      for (int r = 0; r < 4; ++r) {
        int row = rbase + r;
        if (row < M) {
          float v = acc[i][j][r] + bv;
          size_t idx = (size_t)row * ldc + col;
          if (accum) v += Cf[idx];
          if (Cf) Cf[idx] = v;
          if (Cb) Cb[idx] = f2bf(v);
        }
      }
    }
  }
}

// transpose f32 [K][N] -> bf16 [N][K], batched over blockIdx.z
__global__ __launch_bounds__(256) void wtrans(
    const float* __restrict__ src, ushort* __restrict__ dst, int K, int N)
{
  __shared__ float t[32][33];
  size_t zo = (size_t)blockIdx.z * K * N;
  int kb = blockIdx.x * 32, nb = blockIdx.y * 32;
  int tx = threadIdx.x & 31, ty = threadIdx.x >> 5;
#pragma unroll
  for (int r = 0; r < 32; r += 8) {
    int k = kb + ty + r, n = nb + tx;
    if (k < K && n < N) t[ty + r][tx] = src[zo + (size_t)k * N + n];
  }
  __syncthreads();
#pragma unroll
  for (int r = 0; r < 32; r += 8) {
    int n = nb + ty + r, k = kb + tx;
    if (n < N && k < K) dst[zo + (size_t)n * K + k] = f2bf(t[tx][ty + r]);
  }
}

__global__ void conv_bf16(const float* __restrict__ in, ushort* __restrict__ out, int n4) {
  int i = blockIdx.x * blockDim.x + threadIdx.x;
  if (i >= n4) return;
  float4 v = *(const float4*)(in + (size_t)i * 4);
  ushort4 o;
  o.x = f2bf(v.x); o.y = f2bf(v.y); o.z = f2bf(v.z); o.w = f2bf(v.w);
  *(ushort4*)(out + (size_t)i * 4) = o;
}

// ---------------- LayerNorm: one wave per row; writes f32 + bf16 ----------------
__global__ __launch_bounds__(256) void ln_kernel(
    const float* __restrict__ X,
    const float* __restrict__ g, const float* __restrict__ b,
    float* __restrict__ H, ushort* __restrict__ Hbf)
{
  int w = (blockIdx.x * blockDim.x + threadIdx.x) >> 6;
  int lane = threadIdx.x & 63;
  if (w >= NTOT) return;
  int type = (w < NS0) ? 0 : (w < OFF2 ? 1 : 2);
  float4 x = *(const float4*)(X + (size_t)w * 256 + (lane << 2));
  float s = x.x + x.y + x.z + x.w;
  float q = x.x * x.x + x.y * x.y + x.z * x.z + x.w * x.w;
#pragma unroll
  for (int off = 32; off >= 1; off >>= 1) {
    s += __shfl_xor(s, off);
    q += __shfl_xor(q, off);
  }
  float m = s * (1.f / 256.f);
  float var = q * (1.f / 256.f) - m * m;
  float rs = rsqrtf(var + 1e-5f);
  float4 gg = *(const float4*)(g + type * 256 + (lane << 2));
  float4 bb = *(const float4*)(b + type * 256 + (lane << 2));
  float4 o;
  o.x = (x.x - m) * rs * gg.x + bb.x;
  o.y = (x.y - m) * rs * gg.y + bb.y;
  o.z = (x.z - m) * rs * gg.z + bb.z;
  o.w = (x.w - m) * rs * gg.w + bb.w;
  *(float4*)(H + (size_t)w * 256 + (lane << 2)) = o;
  ushort4 ob;
  ob.x = f2bf(o.x); ob.y = f2bf(o.y); ob.z = f2bf(o.z); ob.w = f2bf(o.w);
  *(ushort4*)(Hbf + (size_t)w * 256 + (lane << 2)) = ob;
}

// ---------------- CSR build ----------------
__global__ void csr_hist(const int* __restrict__ ei, int ne, int* __restrict__ deg) {
  int t = blockIdx.x * blockDim.x + threadIdx.x;
  if (t < ne) atomicAdd(&deg[ei[ne + t]], 1);
}
__global__ __launch_bounds__(256) void scan_block(
    const int* __restrict__ in, int n, int* __restrict__ out, int* __restrict__ bsum)
{
  __shared__ int sdata[256];
  int tid = threadIdx.x;
  int base = blockIdx.x * 1024 + tid * 4;
  int v[4]; int s = 0;
#pragma unroll
  for (int j = 0; j < 4; ++j) {
    int x = (base + j < n) ? in[base + j] : 0;
    v[j] = s; s += x;
  }
  sdata[tid] = s;
  __syncthreads();
  int own = s;
  for (int off = 1; off < 256; off <<= 1) {
    int u = (tid >= off) ? sdata[tid - off] : 0;
    __syncthreads();
    sdata[tid] += u;
    __syncthreads();
  }
  int thrExcl = sdata[tid] - own;
#pragma unroll
  for (int j = 0; j < 4; ++j)
    if (base + j < n) out[base + j] = thrExcl + v[j];
  if (tid == 255) bsum[blockIdx.x] = sdata[255];
}
__global__ void scan_bsum(int* __restrict__ bsum, int nb) {
  if (threadIdx.x == 0 && blockIdx.x == 0) {
    int r = 0;
    for (int b = 0; b < nb; ++b) { int t = bsum[b]; bsum[b] = r; r += t; }
    bsum[nb] = r;
  }
}
__global__ void scan_add(int* __restrict__ out, int n, const int* __restrict__ bsum, int nb) {
  int i = blockIdx.x * blockDim.x + threadIdx.x;
  if (i < n) out[i] += bsum[i >> 10];
  else if (i == n) out[n] = bsum[nb];
}
__global__ void csr_scatter(const int* __restrict__ ei, int ne,
                            const int* __restrict__ rowptr, int* __restrict__ cur,
                            int* __restrict__ eidx) {
  int t = blockIdx.x * blockDim.x + threadIdx.x;
  if (t >= ne) return;
  int d = ei[ne + t];
  int pos = rowptr[d] + atomicAdd(&cur[d], 1);
  eidx[pos] = t;
}

// ---------------- edge scores (bf16 gathers, f32 accumulate) ----------------
__global__ __launch_bounds__(256) void edge_scores(
    const int* __restrict__ ei, int ne,
    const ushort* __restrict__ QKV, int dst_off,   // q at col offset 256, ld 768
    const ushort* __restrict__ KRb,
    const float* __restrict__ prel,
    float* __restrict__ SC, size_t sc_off)
{
  int w = (blockIdx.x * blockDim.x + threadIdx.x) >> 6;
  int lane = threadIdx.x & 63;
  if (w >= ne) return;
  int src = ei[w];
  int dst = ei[ne + w];
  ushort4 q4 = *(const ushort4*)(QKV + (size_t)(dst_off + dst) * 768 + 256 + (lane << 2));
  ushort4 k4 = *(const ushort4*)(KRb + (size_t)src * 256 + (lane << 2));
  float s = bf2f(q4.x) * bf2f(k4.x) + bf2f(q4.y) * bf2f(k4.y) +
            bf2f(q4.z) * bf2f(k4.z) + bf2f(q4.w) * bf2f(k4.w);
  s += __shfl_xor(s, 8, 16);
  s += __shfl_xor(s, 4, 16);
  s += __shfl_xor(s, 2, 16);
  s += __shfl_xor(s, 1, 16);
  int h = lane >> 4;
  if ((lane & 15) == 0)
    SC[(sc_off + w) * 4 + h] = s * prel[h] * 0.125f;
}

// ---------------- per-node softmax ----------------
__global__ __launch_bounds__(256) void node_softmax(
    int n,
    const int* __restrict__ rpA, const int* __restrict__ exA, size_t scA,
    const int* __restrict__ rpB, const int* __restrict__ exB, size_t scB,
    float* __restrict__ SC)
{
  int gid = blockIdx.x * blockDim.x + threadIdx.x;
  if (gid >= n * 4) return;
  int nd = gid >> 2, h = gid & 3;
  int a0 = rpA[nd], a1 = rpA[nd + 1];
  int b0 = 0, b1 = 0;
  if (rpB) { b0 = rpB[nd]; b1 = rpB[nd + 1]; }
  if (a1 == a0 && b1 == b0) return;
  float m = -INFINITY;
  for (int i = a0; i < a1; ++i) m = fmaxf(m, SC[(scA + exA[i]) * 4 + h]);
  for (int i = b0; i < b1; ++i) m = fmaxf(m, SC[(scB + exB[i]) * 4 + h]);
  float z = 0.f;
  for (int i = a0; i < a1; ++i) {
    size_t p = (scA + exA[i]) * 4 + h;
    float e = expf(SC[p] - m); SC[p] = e; z += e;
  }
  for (int i = b0; i < b1; ++i) {
    size_t p = (scB + exB[i]) * 4 + h;
    float e = expf(SC[p] - m); SC[p] = e; z += e;
  }
  float inv = 1.f / (z + 1e-16f);
  for (int i = a0; i < a1; ++i) SC[(scA + exA[i]) * 4 + h] *= inv;
  for (int i = b0; i < b1; ++i) SC[(scB + exB[i]) * 4 + h] *= inv;
}

// ---------------- per-node aggregation (bf16 V, bf16 out, GELU fused) ----------------
__global__ __launch_bounds__(256) void node_aggr(
    int n, int dst_off,
    const int* __restrict__ rpA, const int* __restrict__ exA, const int* __restrict__ srcA,
    size_t scA, const ushort* __restrict__ VA,
    const int* __restrict__ rpB, const int* __restrict__ exB, const int* __restrict__ srcB,
    size_t scB, const ushort* __restrict__ VB,
    const float* __restrict__ SC, ushort* __restrict__ AGGb)
{
  int wid = (blockIdx.x * blockDim.x + threadIdx.x) >> 6;
  int lane = threadIdx.x & 63;
  if (wid >= n) return;
  int h = lane >> 4;
  float ax = 0.f, ay = 0.f, az = 0.f, aw = 0.f;
  int a0 = rpA[wid], a1 = rpA[wid + 1];
  for (int i = a0; i < a1; ++i) {
    int ee = exA[i];
    float at = SC[(scA + ee) * 4 + h];
    ushort4 v4 = *(const ushort4*)(VA + (size_t)srcA[ee] * 256 + (lane << 2));
    ax = fmaf(at, bf2f(v4.x), ax);
    ay = fmaf(at, bf2f(v4.y), ay);
    az = fmaf(at, bf2f(v4.z), az);
    aw = fmaf(at, bf2f(v4.w), aw);
  }
  if (rpB) {
    int b0 = rpB[wid], b1 = rpB[wid + 1];
    for (int i = b0; i < b1; ++i) {
      int ee = exB[i];
      float at = SC[(scB + ee) * 4 + h];
      ushort4 v4 = *(const ushort4*)(VB + (size_t)srcB[ee] * 256 + (lane << 2));
      ax = fmaf(at, bf2f(v4.x), ax);
      ay = fmaf(at, bf2f(v4.y), ay);
      az = fmaf(at, bf2f(v4.z), az);
      aw = fmaf(at, bf2f(v4.w), aw);
    }
  }
  ushort4 o;
  o.x = f2bf(gelu_f(ax)); o.y = f2bf(gelu_f(ay));
  o.z = f2bf(gelu_f(az)); o.w = f2bf(gelu_f(aw));
  *(ushort4*)(AGGb + (size_t)(dst_off + wid) * 256 + (lane << 2)) = o;
}

// Xcur = alpha*TMP + (1-alpha)*Hb  (f32 + bf16 out)
__global__ __launch_bounds__(256) void skip_store(
    const float* __restrict__ TMP, const float* __restrict__ Hb,
    const float* __restrict__ skipv, float* __restrict__ Xcur, ushort* __restrict__ Xbf)
{
  int t = blockIdx.x * blockDim.x + threadIdx.x;
  if (t >= NTOT * 64) return;
  int w = t >> 6;
  int f4 = (t & 63) << 2;
  int type = (w < NS0) ? 0 : (w < OFF2 ? 1 : 2);
  float al = 1.f / (1.f + expf(-skipv[type]));
  float4 a = *(const float4*)(TMP + (size_t)w * 256 + f4);
  float4 h = *(const float4*)(Hb + (size_t)w * 256 + f4);
  float4 o;
  o.x = al * a.x + (1.f - al) * h.x;
  o.y = al * a.y + (1.f - al) * h.y;
  o.z = al * a.z + (1.f - al) * h.z;
  o.w = al * a.w + (1.f - al) * h.w;
  *(float4*)(Xcur + (size_t)w * 256 + f4) = o;
  ushort4 ob;
  ob.x = f2bf(o.x); ob.y = f2bf(o.y); ob.z = f2bf(o.z); ob.w = f2bf(o.w);
  *(ushort4*)(Xbf + (size_t)w * 256 + f4) = ob;
}

// ---------------- pooling (no atomics; batch arrays are sorted) ----------------
__global__ void batch_ptr(const int* __restrict__ batch, int n, int* __restrict__ bptr) {
  int b = threadIdx.x;
  if (b > 64) return;
  int lo = 0, hi = n;
  while (lo < hi) { int mid = (lo + hi) >> 1; if (batch[mid] < b) lo = mid + 1; else hi = mid; }
  bptr[b] = lo;
}

__global__ __launch_bounds__(256) void gate_score(
    const float* __restrict__ JK, const float* __restrict__ Wg, const float* __restrict__ bg,
    float* __restrict__ GS, int n)
{
  int w = (blockIdx.x * blockDim.x + threadIdx.x) >> 6;
  int lane = threadIdx.x & 63;
  if (w >= n) return;
  float4 x = *(const float4*)(JK + (size_t)w * 256 + (lane << 2));
  float4 g4 = *(const float4*)(Wg + (lane << 2));
  float s = x.x * g4.x + x.y * g4.y + x.z * g4.z + x.w * g4.w;
#pragma unroll
  for (int off = 32; off >= 1; off >>= 1) s += __shfl_xor(s, off);
  if (lane == 0) GS[w] = s + bg[0];
}

// one block per graph: softmax over contiguous rows + weighted column sum
__global__ __launch_bounds__(256) void pool_graph(
    const float* __restrict__ JK, const float* __restrict__ GS,
    const int* __restrict__ bptr, float* __restrict__ O784, int colOff)
{
  __shared__ float red[256];
  int b = blockIdx.x;
  int lo = bptr[b], hi = bptr[b + 1];
  int tid = threadIdx.x;
  float m = -INFINITY;
  for (int r = lo + tid; r < hi; r += 256) m = fmaxf(m, GS[r]);
  red[tid] = m; __syncthreads();
  for (int s = 128; s >= 1; s >>= 1) {
    if (tid < s) red[tid] = fmaxf(red[tid], red[tid + s]);
    __syncthreads();
  }
  m = red[0]; __syncthreads();
  float z = 0.f;
  for (int r = lo + tid; r < hi; r += 256) z += expf(GS[r] - m);
  red[tid] = z; __syncthreads();
  for (int s = 128; s >= 1; s >>= 1) {
    if (tid < s) red[tid] += red[tid + s];
    __syncthreads();
  }
  z = red[0] + 1e-16f;
  float acc = 0.f;
  for (int r = lo; r < hi; ++r)
    acc += expf(GS[r] - m) * JK[(size_t)r * 256 + tid];
  O784[(size_t)b * 784 + colOff + tid] = acc / z;
}

__global__ void hy_kernel(
    const float* __restrict__ y, const float* __restrict__ W1, const float* __restrict__ b1,
    const float* __restrict__ W2, const float* __restrict__ b2, float* __restrict__ O784)
{
  int r = threadIdx.x;
  if (r >= 64) return;
  float yv = y[r];
  float h1[16];
#pragma unroll
  for (int j = 0; j < 16; ++j) {
    float v = yv * W1[j] + b1[j];
    h1[j] = v > 0.f ? v : 0.2f * v;
  }
#pragma unroll
  for (int c = 0; c < 16; ++c) {
    float s = b2[c];
#pragma unroll
    for (int j = 0; j < 16; ++j) s += h1[j] * W2[j * 16 + c];
    O784[(size_t)r * 784 + 768 + c] = s;
  }
}

__global__ void dense_small(
    const float* __restrict__ A, int K, int N,
    const float* __restrict__ W, const float* __restrict__ b, float* __restrict__ C)
{
  int r = blockIdx.x;
  int c = threadIdx.x;
  if (c >= N) return;
  float s = b[c];
  for (int k = 0; k < K; ++k) s += A[(size_t)r * K + k] * W[(size_t)k * N + c];
  C[(size_t)r * N + c] = s;
}

__global__ void bn_gelu(
    const float* __restrict__ in, const float* __restrict__ g, const float* __restrict__ be,
    float* __restrict__ out, int C)
{
  int c = threadIdx.x;
  if (c >= C) return;
  float s = 0.f, sq = 0.f;
  for (int r = 0; r < 64; ++r) {
    float v = in[r * C + c];
    s += v;
    sq += v * v;
  }
  float m = s * (1.f / 64.f);
  float var = sq * (1.f / 64.f) - m * m;
  float rs = rsqrtf(var + 1e-5f);
  for (int r = 0; r < 64; ++r) {
    float v = (in[r * C + c] - m) * rs * g[c] + be[c];
    out[r * C + c] = gelu_f(v);
  }
}

extern "C" void kernel_launch(void* const* d_in, const int* in_sizes, int n_in,
                              void* d_out, int out_size, void* d_ws, size_t ws_size,
                              hipStream_t stream)
{
  const float* x_in[3] = {(const float*)d_in[0], (const float*)d_in[1], (const float*)d_in[2]};
  const float* y_base = (const float*)d_in[3];
  const float* W_in = (const float*)d_in[4];
  const float* b_in = (const float*)d_in[5];
  const float* ln_g = (const float*)d_in[6];
  const float* ln_b = (const float*)d_in[7];
  const float* W_kqv = (const float*)d_in[8];
  const float* b_kqv = (const float*)d_in[9];
  const float* W_krel = (const float*)d_in[10];
  const float* W_vrel = (const float*)d_in[11];
  const float* p_rel = (const float*)d_in[12];
  const float* W_out = (const float*)d_in[13];
  const float* b_out = (const float*)d_in[14];
  const float* skipv = (const float*)d_in[15];
  const float* W_jk = (const float*)d_in[16];
  const float* b_jk = (const float*)d_in[17];
  const float* W_gate = (const float*)d_in[18];
  const float* b_gate = (const float*)d_in[19];
  const float* W_y1 = (const float*)d_in[20];
  const float* b_y1 = (const float*)d_in[21];
  const float* W_y2 = (const float*)d_in[22];
  const float* b_y2 = (const float*)d_in[23];
  const float* Wg1 = (const float*)d_in[24];
  const float* bg1 = (const float*)d_in[25];
  const float* g1 = (const float*)d_in[26];
  const float* beta1 = (const float*)d_in[27];
  const float* Wg2 = (const float*)d_in[28];
  const float* bg2 = (const float*)d_in[29];
  const float* g2 = (const float*)d_in[30];
  const float* beta2 = (const float*)d_in[31];
  const float* Wg3 = (const float*)d_in[32];
  const float* bg3 = (const float*)d_in[33];
  const int* eis[4] = {(const int*)d_in[34], (const int*)d_in[35], (const int*)d_in[36], (const int*)d_in[37]};
  const int* batchp[3] = {(const int*)d_in[38], (const int*)d_in[39], (const int*)d_in[40]};

  const int NSs[3] = {NS0, NS1, NS2};
  const int offs[3] = {0, OFF1, OFF2};
  const int NEs[4] = {320000, 320000, 160000, 160000};
  const int stt[4] = {0, 1, 0, 2};
  const int dtt[4] = {1, 0, 2, 0};
  const size_t scoff[4] = {0, 320000, 640000, 800000};
  const size_t vroff[4] = {0, 80000, 140000, 220000};
  const int ndst[4] = {60000, 80000, 30000, 80000};

  float* ws = nullptr;
  if (hipGetSymbolAddress((void**)&ws, HIP_SYMBOL(g_ws)) != hipSuccess || !ws) return;

  const size_t NODE = (size_t)NTOT * 256;
  size_t o = 0;
  float* Xcur = ws + o;  o += NODE;
  float* Hb = ws + o;    o += NODE;
  float* TMPo = ws + o;  o += NODE;            // W_out f32 output
  float* JKacc = ws + o; o += NODE;
  float* SC = ws + o;    o += (size_t)960000 * 4;
  float* GS = ws + o;    o += (size_t)NTOT;
  float* O784 = ws + o;  o += (size_t)64 * 784;
  float* BN1 = ws + o;   o += (size_t)64 * 256;
  float* T1 = ws + o;    o += (size_t)64 * 256;
  float* BN2 = ws + o;   o += (size_t)64 * 128;
  float* T2 = ws + o;    o += (size_t)64 * 128;
  // bf16 buffers (float units)
  ushort* QKV = (ushort*)(ws + o);     o += (size_t)NTOT * 768 / 2;
  ushort* Hb_bf = (ushort*)(ws + o);   o += NODE / 2;
  ushort* Xcur_bf = (ushort*)(ws + o); o += NODE / 2;
  ushort* AGGb = (ushort*)(ws + o);    o += NODE / 2;
  ushort* KRb = (ushort*)(ws + o);     o += (size_t)80000 * 256 / 2;
  ushort* VRb = (ushort*)(ws + o);     o += (size_t)250000 * 256 / 2;
  ushort* Xin_bf = (ushort*)(ws + o);  o += (size_t)NTOT * 128 / 2;
  ushort* WT_in = (ushort*)(ws + o);   o += (size_t)3 * 256 * 128 / 2;
  ushort* WT_kqv = (ushort*)(ws + o);  o += (size_t)12 * 768 * 256 / 2;
  ushort* WT_krel = (ushort*)(ws + o); o += (size_t)16 * 256 * 256 / 2;
  ushort* WT_vrel = (ushort*)(ws + o); o += (size_t)16 * 256 * 256 / 2;
  ushort* WT_out = (ushort*)(ws + o);  o += (size_t)12 * 256 * 256 / 2;
  ushort* WT_jk = (ushort*)(ws + o);   o += (size_t)3 * 256 * 1024 / 2;
  // int region (kept last; GEMM A-operand tail over-reads stay inside g_ws)
  int* ib = (int*)(ws + o);
  size_t io = 0;
  int* rp[4]; int* ex[4]; int* degc[4];
  for (int e = 0; e < 4; ++e) { rp[e] = ib + io; io += ndst[e] + 1; }
  for (int e = 0; e < 4; ++e) { ex[e] = ib + io; io += NEs[e]; }
  for (int e = 0; e < 4; ++e) { degc[e] = ib + io; io += ndst[e]; }
  int* bsum = ib + io; io += 257;
  int* bptr3 = ib + io; io += 3 * 65;

  auto gemm = [&](const ushort* A, int lda, const ushort* BT, int ldb, const float* bias,
                  float* Cf, ushort* Cb, int ldc, int M, int N, int K, int accum) {
    dim3 g((M + 127) / 128, N / 128);
    gemm_mfma<<<g, 256, 0, stream>>>(A, lda, BT, ldb, bias, Cf, Cb, ldc, M, K, accum);
  };

  // ---- weight transpose + bf16 convert ----
  wtrans<<<dim3(4, 8, 3), 256, 0, stream>>>(W_in, WT_in, 128, 256);
  wtrans<<<dim3(8, 24, 12), 256, 0, stream>>>(W_kqv, WT_kqv, 256, 768);
  wtrans<<<dim3(8, 8, 16), 256, 0, stream>>>(W_krel, WT_krel, 256, 256);
  wtrans<<<dim3(8, 8, 16), 256, 0, stream>>>(W_vrel, WT_vrel, 256, 256);
  wtrans<<<dim3(8, 8, 12), 256, 0, stream>>>(W_out, WT_out, 256, 256);
  wtrans<<<dim3(32, 8, 3), 256, 0, stream>>>(W_jk, WT_jk, 1024, 256);

  for (int i = 0; i < 3; ++i) {
    int n4 = NSs[i] * 128 / 4;
    conv_bf16<<<(n4 + 255) / 256, 256, 0, stream>>>(x_in[i], Xin_bf + (size_t)offs[i] * 128, n4);
  }

  // ---- CSR per edge type ----
  for (int e = 0; e < 4; ++e) {
    int n = ndst[e], ne = NEs[e];
    int nb = (n + 1023) / 1024;
    hipMemsetAsync(degc[e], 0, n * sizeof(int), stream);
    csr_hist<<<(ne + 255) / 256, 256, 0, stream>>>(eis[e], ne, degc[e]);
    scan_block<<<nb, 256, 0, stream>>>(degc[e], n, rp[e], bsum);
    scan_bsum<<<1, 1, 0, stream>>>(bsum, nb);
    scan_add<<<(n + 256) / 256, 256, 0, stream>>>(rp[e], n, bsum, nb);
    hipMemsetAsync(degc[e], 0, n * sizeof(int), stream);
    csr_scatter<<<(ne + 255) / 256, 256, 0, stream>>>(eis[e], ne, rp[e], degc[e], ex[e]);
  }
  for (int i = 0; i < 3; ++i)
    batch_ptr<<<1, 128, 0, stream>>>(batchp[i], NSs[i], bptr3 + i * 65);

  // ---- input projection -> Xcur (f32) ----
  for (int i = 0; i < 3; ++i)
    gemm(Xin_bf + (size_t)offs[i] * 128, 128, WT_in + (size_t)i * 256 * 128, 128,
         b_in + i * 256, Xcur + (size_t)offs[i] * 256, nullptr, 256, NSs[i], 256, 128, 0);

  for (int l = 0; l < 4; ++l) {
    ln_kernel<<<(NTOT * 64 + 255) / 256, 256, 0, stream>>>(
        Xcur, ln_g + (size_t)l * 3 * 256, ln_b + (size_t)l * 3 * 256, Hb, Hb_bf);

    // fused k|q|v -> QKV bf16 (one N=768 GEMM per type)
    for (int i = 0; i < 3; ++i)
      gemm(Hb_bf + (size_t)offs[i] * 256, 256,
           WT_kqv + ((size_t)l * 3 + i) * 768 * 256, 256,
           b_kqv + ((size_t)l * 3 + i) * 768,
           nullptr, QKV + (size_t)offs[i] * 768, 768, NSs[i], 768, 256, 0);

    // scores per edge type (k_rel GEMM -> bf16 KRb, then gather)
    for (int e = 0; e < 4; ++e) {
      gemm(QKV + (size_t)offs[stt[e]] * 768, 768,
           WT_krel + ((size_t)l * 4 + e) * 256 * 256, 256, nullptr,
           nullptr, KRb, 256, NSs[stt[e]], 256, 256, 0);
      edge_scores<<<(NEs[e] * 64 + 255) / 256, 256, 0, stream>>>(
          eis[e], NEs[e], QKV, offs[dtt[e]], KRb, p_rel + ((size_t)l * 4 + e) * 4, SC, scoff[e]);
    }

    node_softmax<<<(NS0 * 4 + 255) / 256, 256, 0, stream>>>(
        NS0, rp[1], ex[1], scoff[1], rp[3], ex[3], scoff[3], SC);
    node_softmax<<<(NS1 * 4 + 255) / 256, 256, 0, stream>>>(
        NS1, rp[0], ex[0], scoff[0], nullptr, nullptr, 0, SC);
    node_softmax<<<(NS2 * 4 + 255) / 256, 256, 0, stream>>>(
        NS2, rp[2], ex[2], scoff[2], nullptr, nullptr, 0, SC);

    // v_rel per edge type -> VRb (A = v cols of QKV)
    for (int e = 0; e < 4; ++e)
      gemm(QKV + (size_t)offs[stt[e]] * 768 + 512, 768,
           WT_vrel + ((size_t)l * 4 + e) * 256 * 256, 256, nullptr,
           nullptr, VRb + vroff[e] * 256, 256, NSs[stt[e]], 256, 256, 0);

    // per-node aggregation -> AGGb (GELU fused)
    node_aggr<<<(NS0 + 3) / 4, 256, 0, stream>>>(
        NS0, 0,
        rp[1], ex[1], eis[1], scoff[1], VRb + vroff[1] * 256,
        rp[3], ex[3], eis[3], scoff[3], VRb + vroff[3] * 256,
        SC, AGGb);
    node_aggr<<<(NS1 + 3) / 4, 256, 0, stream>>>(
        NS1, OFF1,
        rp[0], ex[0], eis[0], scoff[0], VRb + vroff[0] * 256,
        nullptr, nullptr, nullptr, 0, nullptr,
        SC, AGGb);
    node_aggr<<<(NS2 + 3) / 4, 256, 0, stream>>>(
        NS2, OFF2,
        rp[2], ex[2], eis[2], scoff[2], VRb + vroff[2] * 256,
        nullptr, nullptr, nullptr, 0, nullptr,
        SC, AGGb);

    // W_out -> TMPo (f32)
    for (int i = 0; i < 3; ++i)
      gemm(AGGb + (size_t)offs[i] * 256, 256,
           WT_out + ((size_t)l * 3 + i) * 256 * 256, 256,
           b_out + ((size_t)l * 3 + i) * 256,
           TMPo + (size_t)offs[i] * 256, nullptr, 256, NSs[i], 256, 256, 0);

    skip_store<<<(NTOT * 64 + 255) / 256, 256, 0, stream>>>(
        TMPo, Hb, skipv + l * 3, Xcur, Xcur_bf);

    // JKacc (+)= Xcur_bf @ W_jk[l-slice]
    for (int i = 0; i < 3; ++i)
      gemm(Xcur_bf + (size_t)offs[i] * 256, 256,
           WT_jk + (size_t)i * 256 * 1024 + (size_t)l * 256, 1024,
           (l == 0) ? (b_jk + i * 256) : nullptr,
           JKacc + (size_t)offs[i] * 256, nullptr, 256, NSs[i], 256, 256, (l == 0) ? 0 : 1);
  }

  // ---- gated pooling (no atomics) ----
  for (int i = 0; i < 3; ++i)
    gate_score<<<(NSs[i] * 64 + 255) / 256, 256, 0, stream>>>(
        JKacc + (size_t)offs[i] * 256, W_gate + i * 256, b_gate + i, GS + offs[i], NSs[i]);
  for (int i = 0; i < 3; ++i)
    pool_graph<<<64, 256, 0, stream>>>(
        JKacc + (size_t)offs[i] * 256, GS + offs[i], bptr3 + i * 65, O784, i * 256);

  hy_kernel<<<1, 64, 0, stream>>>(y_base, W_y1, b_y1, W_y2, b_y2, O784);

  // head MLP
  dense_small<<<64, 256, 0, stream>>>(O784, 784, 256, Wg1, bg1, BN1);
  bn_gelu<<<1, 256, 0, stream>>>(BN1, g1, beta1, T1, 256);
  dense_small<<<64, 128, 0, stream>>>(T1, 256, 128, Wg2, bg2, BN2);
  bn_gelu<<<1, 128, 0, stream>>>(BN2, g2, beta2, T2, 128);
  dense_small<<<64, 1, 0, stream>>>(T2, 128, 1, Wg3, bg3, (float*)d_out);
}

// Round 7
// 8390.781 us; speedup vs baseline: 3.8373x; 1.1272x over previous
//
#include <hip/hip_runtime.h>
#include <math.h>

#define NS0 80000
#define NS1 60000
#define NS2 30000
#define NTOT 170000
#define OFF1 80000
#define OFF2 140000

// bulk scratch as device global (harness ws_size too small; allocated at module load)
__device__ float g_ws[372000000];  // ~1.49 GB

typedef __attribute__((ext_vector_type(8))) short bf16x8;
typedef __attribute__((ext_vector_type(4))) float f32x4;

__device__ inline float gelu_f(float x) {
  float x3 = x * x * x;
  return 0.5f * x * (1.0f + tanhf(0.7978845608028654f * (x + 0.044715f * x3)));
}
__device__ inline ushort f2bf(float f) {
  unsigned u = __float_as_uint(f);
  unsigned r = (u + 0x7FFFu + ((u >> 16) & 1u)) >> 16;
  return (ushort)r;
}
__device__ inline float bf2f(ushort u) { return __uint_as_float((unsigned)u << 16); }

// ---- bf16 MFMA GEMM: C[M x N] = A_bf16[M x K] * (BT_bf16[N x K])^T, N = 128*gridDim.y ----
__global__ __launch_bounds__(256) void gemm_mfma(
    const ushort* __restrict__ A, int lda,
    const ushort* __restrict__ BT, int ldb,
    const float* __restrict__ bias,
    float* __restrict__ Cf, ushort* __restrict__ Cb, int ldc,
    int M, int K, int accum)
{
  __shared__ __align__(16) ushort Asl[128 * 32];
  __shared__ __align__(16) ushort Bsl[128 * 32];
  const int tid = threadIdx.x;
  const int w = tid >> 6, l = tid & 63;
  const int wr = (w >> 1) * 64, wc = (w & 1) * 64;
  const int row0 = blockIdx.x * 128;
  const int col0 = blockIdx.y * 128;
  const int lr = l >> 2;
  const int lk = (l & 3) * 8;
  const int fr = l & 15;
  const int fk = (l >> 4) * 8;

  f32x4 acc[4][4];
#pragma unroll
  for (int i = 0; i < 4; ++i)
#pragma unroll
    for (int j = 0; j < 4; ++j) acc[i][j] = (f32x4){0.f, 0.f, 0.f, 0.f};

  for (int k0 = 0; k0 < K; k0 += 32) {
    __syncthreads();
#pragma unroll
    for (int ci = 0; ci < 2; ++ci) {
      int chunk = w * 2 + ci;
      const ushort* ga = A + (size_t)(row0 + chunk * 16 + lr) * lda + k0 + lk;
      __builtin_amdgcn_global_load_lds(
          (const __attribute__((address_space(1))) void*)ga,
          (__attribute__((address_space(3))) void*)&Asl[chunk * 512], 16, 0, 0);
      const ushort* gb = BT + (size_t)(col0 + chunk * 16 + lr) * ldb + k0 + lk;
      __builtin_amdgcn_global_load_lds(
          (const __attribute__((address_space(1))) void*)gb,
          (__attribute__((address_space(3))) void*)&Bsl[chunk * 512], 16, 0, 0);
    }
    __syncthreads();
    bf16x8 af[4], bfr[4];
#pragma unroll
    for (int i = 0; i < 4; ++i)
      af[i] = *(const bf16x8*)&Asl[(wr + i * 16 + fr) * 32 + fk];
#pragma unroll
    for (int j = 0; j < 4; ++j)
      bfr[j] = *(const bf16x8*)&Bsl[(wc + j * 16 + fr) * 32 + fk];
#pragma unroll
    for (int i = 0; i < 4; ++i)
#pragma unroll
      for (int j = 0; j < 4; ++j)
        acc[i][j] = __builtin_amdgcn_mfma_f32_16x16x32_bf16(af[i], bfr[j], acc[i][j], 0, 0, 0);
  }

#pragma unroll
  for (int j = 0; j < 4; ++j) {
    int col = col0 + wc + j * 16 + fr;
    float bv = bias ? bias[col] : 0.f;
#pragma unroll
    for (int i = 0; i < 4; ++i) {
      int rbase = row0 + wr + i * 16 + (l >> 4) * 4;
#pragma unroll
      for (int r = 0; r < 4; ++r) {
        int row = rbase + r;
        if (row < M) {
          float v = acc[i][j][r] + bv;
          size_t idx = (size_t)row * ldc + col;
          if (accum) v += Cf[idx];
          if (Cf) Cf[idx] = v;
          if (Cb) Cb[idx] = f2bf(v);
        }
      }
    }
  }
}

// transpose f32 [K][N] -> bf16 [N][K], batched over blockIdx.z
__global__ __launch_bounds__(256) void wtrans(
    const float* __restrict__ src, ushort* __restrict__ dst, int K, int N)
{
  __shared__ float t[32][33];
  size_t zo = (size_t)blockIdx.z * K * N;
  int kb = blockIdx.x * 32, nb = blockIdx.y * 32;
  int tx = threadIdx.x & 31, ty = threadIdx.x >> 5;
#pragma unroll
  for (int r = 0; r < 32; r += 8) {
    int k = kb + ty + r, n = nb + tx;
    if (k < K && n < N) t[ty + r][tx] = src[zo + (size_t)k * N + n];
  }
  __syncthreads();
#pragma unroll
  for (int r = 0; r < 32; r += 8) {
    int n = nb + ty + r, k = kb + tx;
    if (n < N && k < K) dst[zo + (size_t)n * K + k] = f2bf(t[tx][ty + r]);
  }
}

__global__ void conv_bf16(const float* __restrict__ in, ushort* __restrict__ out, int n4) {
  int i = blockIdx.x * blockDim.x + threadIdx.x;
  if (i >= n4) return;
  float4 v = *(const float4*)(in + (size_t)i * 4);
  ushort4 o;
  o.x = f2bf(v.x); o.y = f2bf(v.y); o.z = f2bf(v.z); o.w = f2bf(v.w);
  *(ushort4*)(out + (size_t)i * 4) = o;
}

// ---------------- LayerNorm ----------------
__global__ __launch_bounds__(256) void ln_kernel(
    const float* __restrict__ X,
    const float* __restrict__ g, const float* __restrict__ b,
    float* __restrict__ H, ushort* __restrict__ Hbf)
{
  int w = (blockIdx.x * blockDim.x + threadIdx.x) >> 6;
  int lane = threadIdx.x & 63;
  if (w >= NTOT) return;
  int type = (w < NS0) ? 0 : (w < OFF2 ? 1 : 2);
  float4 x = *(const float4*)(X + (size_t)w * 256 + (lane << 2));
  float s = x.x + x.y + x.z + x.w;
  float q = x.x * x.x + x.y * x.y + x.z * x.z + x.w * x.w;
#pragma unroll
  for (int off = 32; off >= 1; off >>= 1) {
    s += __shfl_xor(s, off);
    q += __shfl_xor(q, off);
  }
  float m = s * (1.f / 256.f);
  float var = q * (1.f / 256.f) - m * m;
  float rs = rsqrtf(var + 1e-5f);
  float4 gg = *(const float4*)(g + type * 256 + (lane << 2));
  float4 bb = *(const float4*)(b + type * 256 + (lane << 2));
  float4 o;
  o.x = (x.x - m) * rs * gg.x + bb.x;
  o.y = (x.y - m) * rs * gg.y + bb.y;
  o.z = (x.z - m) * rs * gg.z + bb.z;
  o.w = (x.w - m) * rs * gg.w + bb.w;
  *(float4*)(H + (size_t)w * 256 + (lane << 2)) = o;
  ushort4 ob;
  ob.x = f2bf(o.x); ob.y = f2bf(o.y); ob.z = f2bf(o.z); ob.w = f2bf(o.w);
  *(ushort4*)(Hbf + (size_t)w * 256 + (lane << 2)) = ob;
}

// ---------------- CSR build ----------------
__global__ void csr_hist(const int* __restrict__ ei, int ne, int* __restrict__ deg) {
  int t = blockIdx.x * blockDim.x + threadIdx.x;
  if (t < ne) atomicAdd(&deg[ei[ne + t]], 1);
}
__global__ __launch_bounds__(256) void scan_block(
    const int* __restrict__ in, int n, int* __restrict__ out, int* __restrict__ bsum)
{
  __shared__ int sdata[256];
  int tid = threadIdx.x;
  int base = blockIdx.x * 1024 + tid * 4;
  int v[4]; int s = 0;
#pragma unroll
  for (int j = 0; j < 4; ++j) {
    int x = (base + j < n) ? in[base + j] : 0;
    v[j] = s; s += x;
  }
  sdata[tid] = s;
  __syncthreads();
  int own = s;
  for (int off = 1; off < 256; off <<= 1) {
    int u = (tid >= off) ? sdata[tid - off] : 0;
    __syncthreads();
    sdata[tid] += u;
    __syncthreads();
  }
  int thrExcl = sdata[tid] - own;
#pragma unroll
  for (int j = 0; j < 4; ++j)
    if (base + j < n) out[base + j] = thrExcl + v[j];
  if (tid == 255) bsum[blockIdx.x] = sdata[255];
}
__global__ void scan_bsum(int* __restrict__ bsum, int nb) {
  if (threadIdx.x == 0 && blockIdx.x == 0) {
    int r = 0;
    for (int b = 0; b < nb; ++b) { int t = bsum[b]; bsum[b] = r; r += t; }
    bsum[nb] = r;
  }
}
__global__ void scan_add(int* __restrict__ out, int n, const int* __restrict__ bsum, int nb) {
  int i = blockIdx.x * blockDim.x + threadIdx.x;
  if (i < n) out[i] += bsum[i >> 10];
  else if (i == n) out[n] = bsum[nb];
}
// also emits CSR-ordered endpoint arrays
__global__ void csr_scatter(const int* __restrict__ ei, int ne,
                            const int* __restrict__ rowptr, int* __restrict__ cur,
                            int* __restrict__ src_csr, int* __restrict__ dst_csr) {
  int t = blockIdx.x * blockDim.x + threadIdx.x;
  if (t >= ne) return;
  int d = ei[ne + t];
  int pos = rowptr[d] + atomicAdd(&cur[d], 1);
  src_csr[pos] = ei[t];
  dst_csr[pos] = d;
}

// ---------------- edge scores in CSR order (bf16 gathers, f32 accumulate) ----------------
__global__ __launch_bounds__(256) void edge_scores(
    const int* __restrict__ src_csr, const int* __restrict__ dst_csr, int ne,
    const ushort* __restrict__ QKV, int dst_off,   // q at col offset 256, ld 768
    const ushort* __restrict__ KRb,
    const float* __restrict__ prel,
    float* __restrict__ SC, size_t sc_off)
{
  int p = (blockIdx.x * blockDim.x + threadIdx.x) >> 6;
  int lane = threadIdx.x & 63;
  if (p >= ne) return;
  int src = src_csr[p];
  int dst = dst_csr[p];
  ushort4 q4 = *(const ushort4*)(QKV + (size_t)(dst_off + dst) * 768 + 256 + (lane << 2));
  ushort4 k4 = *(const ushort4*)(KRb + (size_t)src * 256 + (lane << 2));
  float s = bf2f(q4.x) * bf2f(k4.x) + bf2f(q4.y) * bf2f(k4.y) +
            bf2f(q4.z) * bf2f(k4.z) + bf2f(q4.w) * bf2f(k4.w);
  s += __shfl_xor(s, 8, 16);
  s += __shfl_xor(s, 4, 16);
  s += __shfl_xor(s, 2, 16);
  s += __shfl_xor(s, 1, 16);
  int h = lane >> 4;
  if ((lane & 15) == 0)
    SC[(sc_off + p) * 4 + h] = s * prel[h] * 0.125f;
}

// ---------------- per-node softmax over CONTIGUOUS CSR score ranges ----------------
__global__ __launch_bounds__(256) void node_softmax(
    int n,
    const int* __restrict__ rpA, size_t scA,
    const int* __restrict__ rpB, size_t scB,
    float* __restrict__ SC)
{
  int gid = blockIdx.x * blockDim.x + threadIdx.x;
  if (gid >= n * 4) return;
  int nd = gid >> 2, h = gid & 3;
  int a0 = rpA[nd], a1 = rpA[nd + 1];
  int b0 = 0, b1 = 0;
  if (rpB) { b0 = rpB[nd]; b1 = rpB[nd + 1]; }
  if (a1 == a0 && b1 == b0) return;
  float m = -INFINITY;
  for (int i = a0; i < a1; ++i) m = fmaxf(m, SC[(scA + i) * 4 + h]);
  for (int i = b0; i < b1; ++i) m = fmaxf(m, SC[(scB + i) * 4 + h]);
  float z = 0.f;
  for (int i = a0; i < a1; ++i) {
    size_t p = (scA + i) * 4 + h;
    float e = expf(SC[p] - m); SC[p] = e; z += e;
  }
  for (int i = b0; i < b1; ++i) {
    size_t p = (scB + i) * 4 + h;
    float e = expf(SC[p] - m); SC[p] = e; z += e;
  }
  float inv = 1.f / (z + 1e-16f);
  for (int i = a0; i < a1; ++i) SC[(scA + i) * 4 + h] *= inv;
  for (int i = b0; i < b1; ++i) SC[(scB + i) * 4 + h] *= inv;
}

// ---------------- per-node aggregation (contiguous SC/src, bf16 V, GELU fused) --------
__global__ __launch_bounds__(256) void node_aggr(
    int n, int dst_off,
    const int* __restrict__ rpA, const int* __restrict__ srcA,
    size_t scA, const ushort* __restrict__ VA,
    const int* __restrict__ rpB, const int* __restrict__ srcB,
    size_t scB, const ushort* __restrict__ VB,
    const float* __restrict__ SC, ushort* __restrict__ AGGb)
{
  int wid = (blockIdx.x * blockDim.x + threadIdx.x) >> 6;
  int lane = threadIdx.x & 63;
  if (wid >= n) return;
  int h = lane >> 4;
  float ax = 0.f, ay = 0.f, az = 0.f, aw = 0.f;
  int a0 = rpA[wid], a1 = rpA[wid + 1];
  for (int i = a0; i < a1; ++i) {
    float at = SC[(scA + i) * 4 + h];
    ushort4 v4 = *(const ushort4*)(VA + (size_t)srcA[i] * 256 + (lane << 2));
    ax = fmaf(at, bf2f(v4.x), ax);
    ay = fmaf(at, bf2f(v4.y), ay);
    az = fmaf(at, bf2f(v4.z), az);
    aw = fmaf(at, bf2f(v4.w), aw);
  }
  if (rpB) {
    int b0 = rpB[wid], b1 = rpB[wid + 1];
    for (int i = b0; i < b1; ++i) {
      float at = SC[(scB + i) * 4 + h];
      ushort4 v4 = *(const ushort4*)(VB + (size_t)srcB[i] * 256 + (lane << 2));
      ax = fmaf(at, bf2f(v4.x), ax);
      ay = fmaf(at, bf2f(v4.y), ay);
      az = fmaf(at, bf2f(v4.z), az);
      aw = fmaf(at, bf2f(v4.w), aw);
    }
  }
  ushort4 o;
  o.x = f2bf(gelu_f(ax)); o.y = f2bf(gelu_f(ay));
  o.z = f2bf(gelu_f(az)); o.w = f2bf(gelu_f(aw));
  *(ushort4*)(AGGb + (size_t)(dst_off + wid) * 256 + (lane << 2)) = o;
}

// Xcur = alpha*TMP + (1-alpha)*Hb  (f32 + bf16 out)
__global__ __launch_bounds__(256) void skip_store(
    const float* __restrict__ TMP, const float* __restrict__ Hb,
    const float* __restrict__ skipv, float* __restrict__ Xcur, ushort* __restrict__ Xbf)
{
  int t = blockIdx.x * blockDim.x + threadIdx.x;
  if (t >= NTOT * 64) return;
  int w = t >> 6;
  int f4 = (t & 63) << 2;
  int type = (w < NS0) ? 0 : (w < OFF2 ? 1 : 2);
  float al = 1.f / (1.f + expf(-skipv[type]));
  float4 a = *(const float4*)(TMP + (size_t)w * 256 + f4);
  float4 h = *(const float4*)(Hb + (size_t)w * 256 + f4);
  float4 o;
  o.x = al * a.x + (1.f - al) * h.x;
  o.y = al * a.y + (1.f - al) * h.y;
  o.z = al * a.z + (1.f - al) * h.z;
  o.w = al * a.w + (1.f - al) * h.w;
  *(float4*)(Xcur + (size_t)w * 256 + f4) = o;
  ushort4 ob;
  ob.x = f2bf(o.x); ob.y = f2bf(o.y); ob.z = f2bf(o.z); ob.w = f2bf(o.w);
  *(ushort4*)(Xbf + (size_t)w * 256 + f4) = ob;
}

// ---------------- pooling (no giant serial loops) ----------------
__global__ void batch_ptr(const int* __restrict__ batch, int n, int* __restrict__ bptr) {
  int b = threadIdx.x;
  if (b > 64) return;
  int lo = 0, hi = n;
  while (lo < hi) { int mid = (lo + hi) >> 1; if (batch[mid] < b) lo = mid + 1; else hi = mid; }
  bptr[b] = lo;
}

__global__ __launch_bounds__(256) void gate_score(
    const float* __restrict__ JK, const float* __restrict__ Wg, const float* __restrict__ bg,
    float* __restrict__ GS, int n)
{
  int w = (blockIdx.x * blockDim.x + threadIdx.x) >> 6;
  int lane = threadIdx.x & 63;
  if (w >= n) return;
  float4 x = *(const float4*)(JK + (size_t)w * 256 + (lane << 2));
  float4 g4 = *(const float4*)(Wg + (lane << 2));
  float s = x.x * g4.x + x.y * g4.y + x.z * g4.z + x.w * g4.w;
#pragma unroll
  for (int off = 32; off >= 1; off >>= 1) s += __shfl_xor(s, off);
  if (lane == 0) GS[w] = s + bg[0];
}

// per-graph max + inv-sum of exp (64 blocks, tiny)
__global__ __launch_bounds__(256) void pool_mz(
    const float* __restrict__ GS, const int* __restrict__ bptr,
    float* __restrict__ MZ)  // MZ[b*2] = m, MZ[b*2+1] = 1/z
{
  __shared__ float red[256];
  int b = blockIdx.x;
  int lo = bptr[b], hi = bptr[b + 1];
  int tid = threadIdx.x;
  float m = -INFINITY;
  for (int r = lo + tid; r < hi; r += 256) m = fmaxf(m, GS[r]);
  red[tid] = m; __syncthreads();
  for (int s = 128; s >= 1; s >>= 1) {
    if (tid < s) red[tid] = fmaxf(red[tid], red[tid + s]);
    __syncthreads();
  }
  m = red[0]; __syncthreads();
  float z = 0.f;
  for (int r = lo + tid; r < hi; r += 256) z += expf(GS[r] - m);
  red[tid] = z; __syncthreads();
  for (int s = 128; s >= 1; s >>= 1) {
    if (tid < s) red[tid] += red[tid + s];
    __syncthreads();
  }
  if (tid == 0) { MZ[b * 2] = m; MZ[b * 2 + 1] = 1.f / (red[0] + 1e-16f); }
}

// chunked weighted column-sum; grid (64 graphs, NCHUNK), atomicAdd per column
#define NCHUNK 16
__global__ __launch_bounds__(256) void pool_partial(
    const float* __restrict__ JK, const float* __restrict__ GS,
    const int* __restrict__ bptr, const float* __restrict__ MZ,
    float* __restrict__ O784, int colOff)
{
  int b = blockIdx.x;
  int c = blockIdx.y;
  int lo = bptr[b], hi = bptr[b + 1];
  int tid = threadIdx.x;
  float m = MZ[b * 2], zinv = MZ[b * 2 + 1];
  float acc = 0.f;
  for (int r = lo + c; r < hi; r += NCHUNK)
    acc += expf(GS[r] - m) * JK[(size_t)r * 256 + tid];
  if (acc != 0.f)
    atomicAdd(&O784[(size_t)b * 784 + colOff + tid], acc * zinv);
}

__global__ void hy_kernel(
    const float* __restrict__ y, const float* __restrict__ W1, const float* __restrict__ b1,
    const float* __restrict__ W2, const float* __restrict__ b2, float* __restrict__ O784)
{
  int r = threadIdx.x;
  if (r >= 64) return;
  float yv = y[r];
  float h1[16];
#pragma unroll
  for (int j = 0; j < 16; ++j) {
    float v = yv * W1[j] + b1[j];
    h1[j] = v > 0.f ? v : 0.2f * v;
  }
#pragma unroll
  for (int c = 0; c < 16; ++c) {
    float s = b2[c];
#pragma unroll
    for (int j = 0; j < 16; ++j) s += h1[j] * W2[j * 16 + c];
    O784[(size_t)r * 784 + 768 + c] = s;
  }
}

__global__ void dense_small(
    const float* __restrict__ A, int K, int N,
    const float* __restrict__ W, const float* __restrict__ b, float* __restrict__ C)
{
  int r = blockIdx.x;
  int c = threadIdx.x;
  if (c >= N) return;
  float s = b[c];
  for (int k = 0; k < K; ++k) s += A[(size_t)r * K + k] * W[(size_t)k * N + c];
  C[(size_t)r * N + c] = s;
}

__global__ void bn_gelu(
    const float* __restrict__ in, const float* __restrict__ g, const float* __restrict__ be,
    float* __restrict__ out, int C)
{
  int c = threadIdx.x;
  if (c >= C) return;
  float s = 0.f, sq = 0.f;
  for (int r = 0; r < 64; ++r) {
    float v = in[r * C + c];
    s += v;
    sq += v * v;
  }
  float m = s * (1.f / 64.f);
  float var = sq * (1.f / 64.f) - m * m;
  float rs = rsqrtf(var + 1e-5f);
  for (int r = 0; r < 64; ++r) {
    float v = (in[r * C + c] - m) * rs * g[c] + be[c];
    out[r * C + c] = gelu_f(v);
  }
}

extern "C" void kernel_launch(void* const* d_in, const int* in_sizes, int n_in,
                              void* d_out, int out_size, void* d_ws, size_t ws_size,
                              hipStream_t stream)
{
  const float* x_in[3] = {(const float*)d_in[0], (const float*)d_in[1], (const float*)d_in[2]};
  const float* y_base = (const float*)d_in[3];
  const float* W_in = (const float*)d_in[4];
  const float* b_in = (const float*)d_in[5];
  const float* ln_g = (const float*)d_in[6];
  const float* ln_b = (const float*)d_in[7];
  const float* W_kqv = (const float*)d_in[8];
  const float* b_kqv = (const float*)d_in[9];
  const float* W_krel = (const float*)d_in[10];
  const float* W_vrel = (const float*)d_in[11];
  const float* p_rel = (const float*)d_in[12];
  const float* W_out = (const float*)d_in[13];
  const float* b_out = (const float*)d_in[14];
  const float* skipv = (const float*)d_in[15];
  const float* W_jk = (const float*)d_in[16];
  const float* b_jk = (const float*)d_in[17];
  const float* W_gate = (const float*)d_in[18];
  const float* b_gate = (const float*)d_in[19];
  const float* W_y1 = (const float*)d_in[20];
  const float* b_y1 = (const float*)d_in[21];
  const float* W_y2 = (const float*)d_in[22];
  const float* b_y2 = (const float*)d_in[23];
  const float* Wg1 = (const float*)d_in[24];
  const float* bg1 = (const float*)d_in[25];
  const float* g1 = (const float*)d_in[26];
  const float* beta1 = (const float*)d_in[27];
  const float* Wg2 = (const float*)d_in[28];
  const float* bg2 = (const float*)d_in[29];
  const float* g2 = (const float*)d_in[30];
  const float* beta2 = (const float*)d_in[31];
  const float* Wg3 = (const float*)d_in[32];
  const float* bg3 = (const float*)d_in[33];
  const int* eis[4] = {(const int*)d_in[34], (const int*)d_in[35], (const int*)d_in[36], (const int*)d_in[37]};
  const int* batchp[3] = {(const int*)d_in[38], (const int*)d_in[39], (const int*)d_in[40]};

  const int NSs[3] = {NS0, NS1, NS2};
  const int offs[3] = {0, OFF1, OFF2};
  const int NEs[4] = {320000, 320000, 160000, 160000};
  const int stt[4] = {0, 1, 0, 2};
  const int dtt[4] = {1, 0, 2, 0};
  const size_t scoff[4] = {0, 320000, 640000, 800000};
  const size_t vroff[4] = {0, 80000, 140000, 220000};
  const int ndst[4] = {60000, 80000, 30000, 80000};

  float* ws = nullptr;
  if (hipGetSymbolAddress((void**)&ws, HIP_SYMBOL(g_ws)) != hipSuccess || !ws) return;

  const size_t NODE = (size_t)NTOT * 256;
  size_t o = 0;
  float* Xcur = ws + o;  o += NODE;
  float* Hb = ws + o;    o += NODE;
  float* TMPo = ws + o;  o += NODE;
  float* JKacc = ws + o; o += NODE;
  float* SC = ws + o;    o += (size_t)960000 * 4;
  float* GS = ws + o;    o += (size_t)NTOT;
  float* MZ = ws + o;    o += 128;
  float* O784 = ws + o;  o += (size_t)64 * 784;
  float* BN1 = ws + o;   o += (size_t)64 * 256;
  float* T1 = ws + o;    o += (size_t)64 * 256;
  float* BN2 = ws + o;   o += (size_t)64 * 128;
  float* T2 = ws + o;    o += (size_t)64 * 128;
  // bf16 buffers (float units)
  ushort* QKV = (ushort*)(ws + o);     o += (size_t)NTOT * 768 / 2;
  ushort* Hb_bf = (ushort*)(ws + o);   o += NODE / 2;
  ushort* Xcur_bf = (ushort*)(ws + o); o += NODE / 2;
  ushort* AGGb = (ushort*)(ws + o);    o += NODE / 2;
  ushort* KRb = (ushort*)(ws + o);     o += (size_t)80000 * 256 / 2;
  ushort* VRb = (ushort*)(ws + o);     o += (size_t)250000 * 256 / 2;
  ushort* Xin_bf = (ushort*)(ws + o);  o += (size_t)NTOT * 128 / 2;
  ushort* WT_in = (ushort*)(ws + o);   o += (size_t)3 * 256 * 128 / 2;
  ushort* WT_kqv = (ushort*)(ws + o);  o += (size_t)12 * 768 * 256 / 2;
  ushort* WT_krel = (ushort*)(ws + o); o += (size_t)16 * 256 * 256 / 2;
  ushort* WT_vrel = (ushort*)(ws + o); o += (size_t)16 * 256 * 256 / 2;
  ushort* WT_out = (ushort*)(ws + o);  o += (size_t)12 * 256 * 256 / 2;
  ushort* WT_jk = (ushort*)(ws + o);   o += (size_t)3 * 256 * 1024 / 2;
  // int region (kept last)
  int* ib = (int*)(ws + o);
  size_t io = 0;
  int* rp[4]; int* srcc[4]; int* dstc[4]; int* degc[4];
  for (int e = 0; e < 4; ++e) { rp[e] = ib + io; io += ndst[e] + 1; }
  for (int e = 0; e < 4; ++e) { srcc[e] = ib + io; io += NEs[e]; }
  for (int e = 0; e < 4; ++e) { dstc[e] = ib + io; io += NEs[e]; }
  for (int e = 0; e < 4; ++e) { degc[e] = ib + io; io += ndst[e]; }
  int* bsum = ib + io; io += 257;
  int* bptr3 = ib + io; io += 3 * 65;

  auto gemm = [&](const ushort* A, int lda, const ushort* BT, int ldb, const float* bias,
                  float* Cf, ushort* Cb, int ldc, int M, int N, int K, int accum) {
    dim3 g((M + 127) / 128, N / 128);
    gemm_mfma<<<g, 256, 0, stream>>>(A, lda, BT, ldb, bias, Cf, Cb, ldc, M, K, accum);
  };

  // ---- weight transpose + bf16 convert ----
  wtrans<<<dim3(4, 8, 3), 256, 0, stream>>>(W_in, WT_in, 128, 256);
  wtrans<<<dim3(8, 24, 12), 256, 0, stream>>>(W_kqv, WT_kqv, 256, 768);
  wtrans<<<dim3(8, 8, 16), 256, 0, stream>>>(W_krel, WT_krel, 256, 256);
  wtrans<<<dim3(8, 8, 16), 256, 0, stream>>>(W_vrel, WT_vrel, 256, 256);
  wtrans<<<dim3(8, 8, 12), 256, 0, stream>>>(W_out, WT_out, 256, 256);
  wtrans<<<dim3(32, 8, 3), 256, 0, stream>>>(W_jk, WT_jk, 1024, 256);

  for (int i = 0; i < 3; ++i) {
    int n4 = NSs[i] * 128 / 4;
    conv_bf16<<<(n4 + 255) / 256, 256, 0, stream>>>(x_in[i], Xin_bf + (size_t)offs[i] * 128, n4);
  }

  // ---- CSR per edge type ----
  for (int e = 0; e < 4; ++e) {
    int n = ndst[e], ne = NEs[e];
    int nb = (n + 1023) / 1024;
    hipMemsetAsync(degc[e], 0, n * sizeof(int), stream);
    csr_hist<<<(ne + 255) / 256, 256, 0, stream>>>(eis[e], ne, degc[e]);
    scan_block<<<nb, 256, 0, stream>>>(degc[e], n, rp[e], bsum);
    scan_bsum<<<1, 1, 0, stream>>>(bsum, nb);
    scan_add<<<(n + 256) / 256, 256, 0, stream>>>(rp[e], n, bsum, nb);
    hipMemsetAsync(degc[e], 0, n * sizeof(int), stream);
    csr_scatter<<<(ne + 255) / 256, 256, 0, stream>>>(eis[e], ne, rp[e], degc[e], srcc[e], dstc[e]);
  }
  for (int i = 0; i < 3; ++i)
    batch_ptr<<<1, 128, 0, stream>>>(batchp[i], NSs[i], bptr3 + i * 65);

  // ---- input projection -> Xcur (f32) ----
  for (int i = 0; i < 3; ++i)
    gemm(Xin_bf + (size_t)offs[i] * 128, 128, WT_in + (size_t)i * 256 * 128, 128,
         b_in + i * 256, Xcur + (size_t)offs[i] * 256, nullptr, 256, NSs[i], 256, 128, 0);

  for (int l = 0; l < 4; ++l) {
    ln_kernel<<<(NTOT * 64 + 255) / 256, 256, 0, stream>>>(
        Xcur, ln_g + (size_t)l * 3 * 256, ln_b + (size_t)l * 3 * 256, Hb, Hb_bf);

    // fused k|q|v -> QKV bf16
    for (int i = 0; i < 3; ++i)
      gemm(Hb_bf + (size_t)offs[i] * 256, 256,
           WT_kqv + ((size_t)l * 3 + i) * 768 * 256, 256,
           b_kqv + ((size_t)l * 3 + i) * 768,
           nullptr, QKV + (size_t)offs[i] * 768, 768, NSs[i], 768, 256, 0);

    // scores per edge type
    for (int e = 0; e < 4; ++e) {
      gemm(QKV + (size_t)offs[stt[e]] * 768, 768,
           WT_krel + ((size_t)l * 4 + e) * 256 * 256, 256, nullptr,
           nullptr, KRb, 256, NSs[stt[e]], 256, 256, 0);
      edge_scores<<<(NEs[e] * 64 + 255) / 256, 256, 0, stream>>>(
          srcc[e], dstc[e], NEs[e], QKV, offs[dtt[e]], KRb,
          p_rel + ((size_t)l * 4 + e) * 4, SC, scoff[e]);
    }

    node_softmax<<<(NS0 * 4 + 255) / 256, 256, 0, stream>>>(
        NS0, rp[1], scoff[1], rp[3], scoff[3], SC);
    node_softmax<<<(NS1 * 4 + 255) / 256, 256, 0, stream>>>(
        NS1, rp[0], scoff[0], nullptr, 0, SC);
    node_softmax<<<(NS2 * 4 + 255) / 256, 256, 0, stream>>>(
        NS2, rp[2], scoff[2], nullptr, 0, SC);

    // v_rel per edge type -> VRb
    for (int e = 0; e < 4; ++e)
      gemm(QKV + (size_t)offs[stt[e]] * 768 + 512, 768,
           WT_vrel + ((size_t)l * 4 + e) * 256 * 256, 256, nullptr,
           nullptr, VRb + vroff[e] * 256, 256, NSs[stt[e]], 256, 256, 0);

    // per-node aggregation -> AGGb
    node_aggr<<<(NS0 + 3) / 4, 256, 0, stream>>>(
        NS0, 0,
        rp[1], srcc[1], scoff[1], VRb + vroff[1] * 256,
        rp[3], srcc[3], scoff[3], VRb + vroff[3] * 256,
        SC, AGGb);
    node_aggr<<<(NS1 + 3) / 4, 256, 0, stream>>>(
        NS1, OFF1,
        rp[0], srcc[0], scoff[0], VRb + vroff[0] * 256,
        nullptr, nullptr, 0, nullptr,
        SC, AGGb);
    node_aggr<<<(NS2 + 3) / 4, 256, 0, stream>>>(
        NS2, OFF2,
        rp[2], srcc[2], scoff[2], VRb + vroff[2] * 256,
        nullptr, nullptr, 0, nullptr,
        SC, AGGb);

    // W_out -> TMPo (f32)
    for (int i = 0; i < 3; ++i)
      gemm(AGGb + (size_t)offs[i] * 256, 256,
           WT_out + ((size_t)l * 3 + i) * 256 * 256, 256,
           b_out + ((size_t)l * 3 + i) * 256,
           TMPo + (size_t)offs[i] * 256, nullptr, 256, NSs[i], 256, 256, 0);

    skip_store<<<(NTOT * 64 + 255) / 256, 256, 0, stream>>>(
        TMPo, Hb, skipv + l * 3, Xcur, Xcur_bf);

    // JKacc (+)= Xcur_bf @ W_jk[l-slice]
    for (int i = 0; i < 3; ++i)
      gemm(Xcur_bf + (size_t)offs[i] * 256, 256,
           WT_jk + (size_t)i * 256 * 1024 + (size_t)l * 256, 1024,
           (l == 0) ? (b_jk + i * 256) : nullptr,
           JKacc + (size_t)offs[i] * 256, nullptr, 256, NSs[i], 256, 256, (l == 0) ? 0 : 1);
  }

  // ---- gated pooling ----
  hipMemsetAsync(O784, 0, (size_t)64 * 784 * sizeof(float), stream);
  for (int i = 0; i < 3; ++i)
    gate_score<<<(NSs[i] * 64 + 255) / 256, 256, 0, stream>>>(
        JKacc + (size_t)offs[i] * 256, W_gate + i * 256, b_gate + i, GS + offs[i], NSs[i]);
  for (int i = 0; i < 3; ++i) {
    pool_mz<<<64, 256, 0, stream>>>(GS + offs[i], bptr3 + i * 65, MZ);
    pool_partial<<<dim3(64, NCHUNK), 256, 0, stream>>>(
        JKacc + (size_t)offs[i] * 256, GS + offs[i], bptr3 + i * 65, MZ, O784, i * 256);
  }

  hy_kernel<<<1, 64, 0, stream>>>(y_base, W_y1, b_y1, W_y2, b_y2, O784);

  // head MLP
  dense_small<<<64, 256, 0, stream>>>(O784, 784, 256, Wg1, bg1, BN1);
  bn_gelu<<<1, 256, 0, stream>>>(BN1, g1, beta1, T1, 256);
  dense_small<<<64, 128, 0, stream>>>(T1, 256, 128, Wg2, bg2, BN2);
  bn_gelu<<<1, 128, 0, stream>>>(BN2, g2, beta2, T2, 128);
  dense_small<<<64, 1, 0, stream>>>(T2, 128, 1, Wg3, bg3, (float*)d_out);
}

// Round 8
// 8060.910 us; speedup vs baseline: 3.9943x; 1.0409x over previous
//
#include <hip/hip_runtime.h>
#include <math.h>

#define NS0 80000
#define NS1 60000
#define NS2 30000
#define NTOT 170000
#define OFF1 80000
#define OFF2 140000

// bulk scratch as device global (harness ws_size too small; allocated at module load)
__device__ float g_ws[372000000];  // ~1.49 GB

typedef __attribute__((ext_vector_type(8))) short bf16x8;
typedef __attribute__((ext_vector_type(4))) float f32x4;

__device__ inline float gelu_f(float x) {
  float x3 = x * x * x;
  return 0.5f * x * (1.0f + tanhf(0.7978845608028654f * (x + 0.044715f * x3)));
}
__device__ inline ushort f2bf(float f) {
  unsigned u = __float_as_uint(f);
  unsigned r = (u + 0x7FFFu + ((u >> 16) & 1u)) >> 16;
  return (ushort)r;
}
__device__ inline float bf2f(ushort u) { return __uint_as_float((unsigned)u << 16); }

// ---- bf16 MFMA GEMM: C[M x N] = A_bf16[M x K] * (BT_bf16[N x K])^T, N = 128*gridDim.y ----
__global__ __launch_bounds__(256) void gemm_mfma(
    const ushort* __restrict__ A, int lda,
    const ushort* __restrict__ BT, int ldb,
    const float* __restrict__ bias,
    float* __restrict__ Cf, ushort* __restrict__ Cb, int ldc,
    int M, int K, int accum)
{
  __shared__ __align__(16) ushort Asl[128 * 32];
  __shared__ __align__(16) ushort Bsl[128 * 32];
  const int tid = threadIdx.x;
  const int w = tid >> 6, l = tid & 63;
  const int wr = (w >> 1) * 64, wc = (w & 1) * 64;
  const int row0 = blockIdx.x * 128;
  const int col0 = blockIdx.y * 128;
  const int lr = l >> 2;
  const int lk = (l & 3) * 8;
  const int fr = l & 15;
  const int fk = (l >> 4) * 8;

  f32x4 acc[4][4];
#pragma unroll
  for (int i = 0; i < 4; ++i)
#pragma unroll
    for (int j = 0; j < 4; ++j) acc[i][j] = (f32x4){0.f, 0.f, 0.f, 0.f};

  for (int k0 = 0; k0 < K; k0 += 32) {
    __syncthreads();
#pragma unroll
    for (int ci = 0; ci < 2; ++ci) {
      int chunk = w * 2 + ci;
      const ushort* ga = A + (size_t)(row0 + chunk * 16 + lr) * lda + k0 + lk;
      __builtin_amdgcn_global_load_lds(
          (const __attribute__((address_space(1))) void*)ga,
          (__attribute__((address_space(3))) void*)&Asl[chunk * 512], 16, 0, 0);
      const ushort* gb = BT + (size_t)(col0 + chunk * 16 + lr) * ldb + k0 + lk;
      __builtin_amdgcn_global_load_lds(
          (const __attribute__((address_space(1))) void*)gb,
          (__attribute__((address_space(3))) void*)&Bsl[chunk * 512], 16, 0, 0);
    }
    __syncthreads();
    bf16x8 af[4], bfr[4];
#pragma unroll
    for (int i = 0; i < 4; ++i)
      af[i] = *(const bf16x8*)&Asl[(wr + i * 16 + fr) * 32 + fk];
#pragma unroll
    for (int j = 0; j < 4; ++j)
      bfr[j] = *(const bf16x8*)&Bsl[(wc + j * 16 + fr) * 32 + fk];
#pragma unroll
    for (int i = 0; i < 4; ++i)
#pragma unroll
      for (int j = 0; j < 4; ++j)
        acc[i][j] = __builtin_amdgcn_mfma_f32_16x16x32_bf16(af[i], bfr[j], acc[i][j], 0, 0, 0);
  }

#pragma unroll
  for (int j = 0; j < 4; ++j) {
    int col = col0 + wc + j * 16 + fr;
    float bv = bias ? bias[col] : 0.f;
#pragma unroll
    for (int i = 0; i < 4; ++i) {
      int rbase = row0 + wr + i * 16 + (l >> 4) * 4;
#pragma unroll
      for (int r = 0; r < 4; ++r) {
        int row = rbase + r;
        if (row < M) {
          float v = acc[i][j][r] + bv;
          size_t idx = (size_t)row * ldc + col;
          if (accum) v += Cf[idx];
          if (Cf) Cf[idx] = v;
          if (Cb) Cb[idx] = f2bf(v);
        }
      }
    }
  }
}

// transpose f32 [K][N] -> bf16 [N][K], batched over blockIdx.z
__global__ __launch_bounds__(256) void wtrans(
    const float* __restrict__ src, ushort* __restrict__ dst, int K, int N)
{
  __shared__ float t[32][33];
  size_t zo = (size_t)blockIdx.z * K * N;
  int kb = blockIdx.x * 32, nb = blockIdx.y * 32;
  int tx = threadIdx.x & 31, ty = threadIdx.x >> 5;
#pragma unroll
  for (int r = 0; r < 32; r += 8) {
    int k = kb + ty + r, n = nb + tx;
    if (k < K && n < N) t[ty + r][tx] = src[zo + (size_t)k * N + n];
  }
  __syncthreads();
#pragma unroll
  for (int r = 0; r < 32; r += 8) {
    int n = nb + ty + r, k = kb + tx;
    if (n < N && k < K) dst[zo + (size_t)n * K + k] = f2bf(t[tx][ty + r]);
  }
}

// transpose f32 [K][N] -> f32 [N][K]
__global__ __launch_bounds__(256) void wtrans_f32(
    const float* __restrict__ src, float* __restrict__ dst, int K, int N)
{
  __shared__ float t[32][33];
  int kb = blockIdx.x * 32, nb = blockIdx.y * 32;
  int tx = threadIdx.x & 31, ty = threadIdx.x >> 5;
#pragma unroll
  for (int r = 0; r < 32; r += 8) {
    int k = kb + ty + r, n = nb + tx;
    if (k < K && n < N) t[ty + r][tx] = src[(size_t)k * N + n];
  }
  __syncthreads();
#pragma unroll
  for (int r = 0; r < 32; r += 8) {
    int n = nb + ty + r, k = kb + tx;
    if (n < N && k < K) dst[(size_t)n * K + k] = t[tx][ty + r];
  }
}

__global__ void conv_bf16(const float* __restrict__ in, ushort* __restrict__ out, int n4) {
  int i = blockIdx.x * blockDim.x + threadIdx.x;
  if (i >= n4) return;
  float4 v = *(const float4*)(in + (size_t)i * 4);
  ushort4 o;
  o.x = f2bf(v.x); o.y = f2bf(v.y); o.z = f2bf(v.z); o.w = f2bf(v.w);
  *(ushort4*)(out + (size_t)i * 4) = o;
}

// ---------------- LayerNorm ----------------
__global__ __launch_bounds__(256) void ln_kernel(
    const float* __restrict__ X,
    const float* __restrict__ g, const float* __restrict__ b,
    float* __restrict__ H, ushort* __restrict__ Hbf)
{
  int w = (blockIdx.x * blockDim.x + threadIdx.x) >> 6;
  int lane = threadIdx.x & 63;
  if (w >= NTOT) return;
  int type = (w < NS0) ? 0 : (w < OFF2 ? 1 : 2);
  float4 x = *(const float4*)(X + (size_t)w * 256 + (lane << 2));
  float s = x.x + x.y + x.z + x.w;
  float q = x.x * x.x + x.y * x.y + x.z * x.z + x.w * x.w;
#pragma unroll
  for (int off = 32; off >= 1; off >>= 1) {
    s += __shfl_xor(s, off);
    q += __shfl_xor(q, off);
  }
  float m = s * (1.f / 256.f);
  float var = q * (1.f / 256.f) - m * m;
  float rs = rsqrtf(var + 1e-5f);
  float4 gg = *(const float4*)(g + type * 256 + (lane << 2));
  float4 bb = *(const float4*)(b + type * 256 + (lane << 2));
  float4 o;
  o.x = (x.x - m) * rs * gg.x + bb.x;
  o.y = (x.y - m) * rs * gg.y + bb.y;
  o.z = (x.z - m) * rs * gg.z + bb.z;
  o.w = (x.w - m) * rs * gg.w + bb.w;
  *(float4*)(H + (size_t)w * 256 + (lane << 2)) = o;
  ushort4 ob;
  ob.x = f2bf(o.x); ob.y = f2bf(o.y); ob.z = f2bf(o.z); ob.w = f2bf(o.w);
  *(ushort4*)(Hbf + (size_t)w * 256 + (lane << 2)) = ob;
}

// ---------------- CSR build ----------------
__global__ void csr_hist(const int* __restrict__ ei, int ne, int* __restrict__ deg) {
  int t = blockIdx.x * blockDim.x + threadIdx.x;
  if (t < ne) atomicAdd(&deg[ei[ne + t]], 1);
}
__global__ __launch_bounds__(256) void scan_block(
    const int* __restrict__ in, int n, int* __restrict__ out, int* __restrict__ bsum)
{
  __shared__ int sdata[256];
  int tid = threadIdx.x;
  int base = blockIdx.x * 1024 + tid * 4;
  int v[4]; int s = 0;
#pragma unroll
  for (int j = 0; j < 4; ++j) {
    int x = (base + j < n) ? in[base + j] : 0;
    v[j] = s; s += x;
  }
  sdata[tid] = s;
  __syncthreads();
  int own = s;
  for (int off = 1; off < 256; off <<= 1) {
    int u = (tid >= off) ? sdata[tid - off] : 0;
    __syncthreads();
    sdata[tid] += u;
    __syncthreads();
  }
  int thrExcl = sdata[tid] - own;
#pragma unroll
  for (int j = 0; j < 4; ++j)
    if (base + j < n) out[base + j] = thrExcl + v[j];
  if (tid == 255) bsum[blockIdx.x] = sdata[255];
}
__global__ void scan_bsum(int* __restrict__ bsum, int nb) {
  if (threadIdx.x == 0 && blockIdx.x == 0) {
    int r = 0;
    for (int b = 0; b < nb; ++b) { int t = bsum[b]; bsum[b] = r; r += t; }
    bsum[nb] = r;
  }
}
__global__ void scan_add(int* __restrict__ out, int n, const int* __restrict__ bsum, int nb) {
  int i = blockIdx.x * blockDim.x + threadIdx.x;
  if (i < n) out[i] += bsum[i >> 10];
  else if (i == n) out[n] = bsum[nb];
}
// also emits CSR-ordered endpoint arrays
__global__ void csr_scatter(const int* __restrict__ ei, int ne,
                            const int* __restrict__ rowptr, int* __restrict__ cur,
                            int* __restrict__ src_csr, int* __restrict__ dst_csr) {
  int t = blockIdx.x * blockDim.x + threadIdx.x;
  if (t >= ne) return;
  int d = ei[ne + t];
  int pos = rowptr[d] + atomicAdd(&cur[d], 1);
  src_csr[pos] = ei[t];
  dst_csr[pos] = d;
}

// ---------------- edge scores in CSR order (bf16 gathers, f32 accumulate) ----------------
__global__ __launch_bounds__(256) void edge_scores(
    const int* __restrict__ src_csr, const int* __restrict__ dst_csr, int ne,
    const ushort* __restrict__ QKV, int dst_off,   // q at col offset 256, ld 768
    const ushort* __restrict__ KRb,
    const float* __restrict__ prel,
    float* __restrict__ SC, size_t sc_off)
{
  int p = (blockIdx.x * blockDim.x + threadIdx.x) >> 6;
  int lane = threadIdx.x & 63;
  if (p >= ne) return;
  int src = src_csr[p];
  int dst = dst_csr[p];
  ushort4 q4 = *(const ushort4*)(QKV + (size_t)(dst_off + dst) * 768 + 256 + (lane << 2));
  ushort4 k4 = *(const ushort4*)(KRb + (size_t)src * 256 + (lane << 2));
  float s = bf2f(q4.x) * bf2f(k4.x) + bf2f(q4.y) * bf2f(k4.y) +
            bf2f(q4.z) * bf2f(k4.z) + bf2f(q4.w) * bf2f(k4.w);
  s += __shfl_xor(s, 8, 16);
  s += __shfl_xor(s, 4, 16);
  s += __shfl_xor(s, 2, 16);
  s += __shfl_xor(s, 1, 16);
  int h = lane >> 4;
  if ((lane & 15) == 0)
    SC[(sc_off + p) * 4 + h] = s * prel[h] * 0.125f;
}

// ---------------- per-node softmax over CONTIGUOUS CSR score ranges ----------------
__global__ __launch_bounds__(256) void node_softmax(
    int n,
    const int* __restrict__ rpA, size_t scA,
    const int* __restrict__ rpB, size_t scB,
    float* __restrict__ SC)
{
  int gid = blockIdx.x * blockDim.x + threadIdx.x;
  if (gid >= n * 4) return;
  int nd = gid >> 2, h = gid & 3;
  int a0 = rpA[nd], a1 = rpA[nd + 1];
  int b0 = 0, b1 = 0;
  if (rpB) { b0 = rpB[nd]; b1 = rpB[nd + 1]; }
  if (a1 == a0 && b1 == b0) return;
  float m = -INFINITY;
  for (int i = a0; i < a1; ++i) m = fmaxf(m, SC[(scA + i) * 4 + h]);
  for (int i = b0; i < b1; ++i) m = fmaxf(m, SC[(scB + i) * 4 + h]);
  float z = 0.f;
  for (int i = a0; i < a1; ++i) {
    size_t p = (scA + i) * 4 + h;
    float e = expf(SC[p] - m); SC[p] = e; z += e;
  }
  for (int i = b0; i < b1; ++i) {
    size_t p = (scB + i) * 4 + h;
    float e = expf(SC[p] - m); SC[p] = e; z += e;
  }
  float inv = 1.f / (z + 1e-16f);
  for (int i = a0; i < a1; ++i) SC[(scA + i) * 4 + h] *= inv;
  for (int i = b0; i < b1; ++i) SC[(scB + i) * 4 + h] *= inv;
}

// ---------------- per-node aggregation (contiguous SC/src, bf16 V, GELU fused) --------
__global__ __launch_bounds__(256) void node_aggr(
    int n, int dst_off,
    const int* __restrict__ rpA, const int* __restrict__ srcA,
    size_t scA, const ushort* __restrict__ VA,
    const int* __restrict__ rpB, const int* __restrict__ srcB,
    size_t scB, const ushort* __restrict__ VB,
    const float* __restrict__ SC, ushort* __restrict__ AGGb)
{
  int wid = (blockIdx.x * blockDim.x + threadIdx.x) >> 6;
  int lane = threadIdx.x & 63;
  if (wid >= n) return;
  int h = lane >> 4;
  float ax = 0.f, ay = 0.f, az = 0.f, aw = 0.f;
  int a0 = rpA[wid], a1 = rpA[wid + 1];
  for (int i = a0; i < a1; ++i) {
    float at = SC[(scA + i) * 4 + h];
    ushort4 v4 = *(const ushort4*)(VA + (size_t)srcA[i] * 256 + (lane << 2));
    ax = fmaf(at, bf2f(v4.x), ax);
    ay = fmaf(at, bf2f(v4.y), ay);
    az = fmaf(at, bf2f(v4.z), az);
    aw = fmaf(at, bf2f(v4.w), aw);
  }
  if (rpB) {
    int b0 = rpB[wid], b1 = rpB[wid + 1];
    for (int i = b0; i < b1; ++i) {
      float at = SC[(scB + i) * 4 + h];
      ushort4 v4 = *(const ushort4*)(VB + (size_t)srcB[i] * 256 + (lane << 2));
      ax = fmaf(at, bf2f(v4.x), ax);
      ay = fmaf(at, bf2f(v4.y), ay);
      az = fmaf(at, bf2f(v4.z), az);
      aw = fmaf(at, bf2f(v4.w), aw);
    }
  }
  ushort4 o;
  o.x = f2bf(gelu_f(ax)); o.y = f2bf(gelu_f(ay));
  o.z = f2bf(gelu_f(az)); o.w = f2bf(gelu_f(aw));
  *(ushort4*)(AGGb + (size_t)(dst_off + wid) * 256 + (lane << 2)) = o;
}

// Xcur = alpha*TMP + (1-alpha)*Hb  (f32 + bf16 out)
__global__ __launch_bounds__(256) void skip_store(
    const float* __restrict__ TMP, const float* __restrict__ Hb,
    const float* __restrict__ skipv, float* __restrict__ Xcur, ushort* __restrict__ Xbf)
{
  int t = blockIdx.x * blockDim.x + threadIdx.x;
  if (t >= NTOT * 64) return;
  int w = t >> 6;
  int f4 = (t & 63) << 2;
  int type = (w < NS0) ? 0 : (w < OFF2 ? 1 : 2);
  float al = 1.f / (1.f + expf(-skipv[type]));
  float4 a = *(const float4*)(TMP + (size_t)w * 256 + f4);
  float4 h = *(const float4*)(Hb + (size_t)w * 256 + f4);
  float4 o;
  o.x = al * a.x + (1.f - al) * h.x;
  o.y = al * a.y + (1.f - al) * h.y;
  o.z = al * a.z + (1.f - al) * h.z;
  o.w = al * a.w + (1.f - al) * h.w;
  *(float4*)(Xcur + (size_t)w * 256 + f4) = o;
  ushort4 ob;
  ob.x = f2bf(o.x); ob.y = f2bf(o.y); ob.z = f2bf(o.z); ob.w = f2bf(o.w);
  *(ushort4*)(Xbf + (size_t)w * 256 + f4) = ob;
}

// ---------------- pooling ----------------
__global__ void batch_ptr(const int* __restrict__ batch, int n, int* __restrict__ bptr) {
  int b = threadIdx.x;
  if (b > 64) return;
  int lo = 0, hi = n;
  while (lo < hi) { int mid = (lo + hi) >> 1; if (batch[mid] < b) lo = mid + 1; else hi = mid; }
  bptr[b] = lo;
}

__global__ __launch_bounds__(256) void gate_score(
    const float* __restrict__ JK, const float* __restrict__ Wg, const float* __restrict__ bg,
    float* __restrict__ GS, int n)
{
  int w = (blockIdx.x * blockDim.x + threadIdx.x) >> 6;
  int lane = threadIdx.x & 63;
  if (w >= n) return;
  float4 x = *(const float4*)(JK + (size_t)w * 256 + (lane << 2));
  float4 g4 = *(const float4*)(Wg + (lane << 2));
  float s = x.x * g4.x + x.y * g4.y + x.z * g4.z + x.w * g4.w;
#pragma unroll
  for (int off = 32; off >= 1; off >>= 1) s += __shfl_xor(s, off);
  if (lane == 0) GS[w] = s + bg[0];
}

__global__ __launch_bounds__(256) void pool_mz(
    const float* __restrict__ GS, const int* __restrict__ bptr,
    float* __restrict__ MZ)
{
  __shared__ float red[256];
  int b = blockIdx.x;
  int lo = bptr[b], hi = bptr[b + 1];
  int tid = threadIdx.x;
  float m = -INFINITY;
  for (int r = lo + tid; r < hi; r += 256) m = fmaxf(m, GS[r]);
  red[tid] = m; __syncthreads();
  for (int s = 128; s >= 1; s >>= 1) {
    if (tid < s) red[tid] = fmaxf(red[tid], red[tid + s]);
    __syncthreads();
  }
  m = red[0]; __syncthreads();
  float z = 0.f;
  for (int r = lo + tid; r < hi; r += 256) z += expf(GS[r] - m);
  red[tid] = z; __syncthreads();
  for (int s = 128; s >= 1; s >>= 1) {
    if (tid < s) red[tid] += red[tid + s];
    __syncthreads();
  }
  if (tid == 0) { MZ[b * 2] = m; MZ[b * 2 + 1] = 1.f / (red[0] + 1e-16f); }
}

#define NCHUNK 16
__global__ __launch_bounds__(256) void pool_partial(
    const float* __restrict__ JK, const float* __restrict__ GS,
    const int* __restrict__ bptr, const float* __restrict__ MZ,
    float* __restrict__ O784, int colOff)
{
  int b = blockIdx.x;
  int c = blockIdx.y;
  int lo = bptr[b], hi = bptr[b + 1];
  int tid = threadIdx.x;
  float m = MZ[b * 2], zinv = MZ[b * 2 + 1];
  float acc = 0.f;
  for (int r = lo + c; r < hi; r += NCHUNK)
    acc += expf(GS[r] - m) * JK[(size_t)r * 256 + tid];
  if (acc != 0.f)
    atomicAdd(&O784[(size_t)b * 784 + colOff + tid], acc * zinv);
}

__global__ void hy_kernel(
    const float* __restrict__ y, const float* __restrict__ W1, const float* __restrict__ b1,
    const float* __restrict__ W2, const float* __restrict__ b2, float* __restrict__ O784)
{
  int r = threadIdx.x;
  if (r >= 64) return;
  float yv = y[r];
  float h1[16];
#pragma unroll
  for (int j = 0; j < 16; ++j) {
    float v = yv * W1[j] + b1[j];
    h1[j] = v > 0.f ? v : 0.2f * v;
  }
#pragma unroll
  for (int c = 0; c < 16; ++c) {
    float s = b2[c];
#pragma unroll
    for (int j = 0; j < 16; ++j) s += h1[j] * W2[j * 16 + c];
    O784[(size_t)r * 784 + 768 + c] = s;
  }
}

// ---------------- head: one wave per output element, K-parallel reduce ----------------
__global__ __launch_bounds__(256) void dense_wave(
    const float* __restrict__ A, const float* __restrict__ WT,
    const float* __restrict__ bias, float* __restrict__ C,
    int M, int N, int K)
{
  int gw = (blockIdx.x * blockDim.x + threadIdx.x) >> 6;
  int lane = threadIdx.x & 63;
  if (gw >= M * N) return;
  int r = gw / N, c = gw - r * N;
  const float* a = A + (size_t)r * K;
  const float* wv = WT + (size_t)c * K;
  float s = 0.f;
  for (int k = lane; k < K; k += 64) s += a[k] * wv[k];
#pragma unroll
  for (int off = 32; off >= 1; off >>= 1) s += __shfl_xor(s, off);
  if (lane == 0) C[(size_t)r * N + c] = s + (bias ? bias[c] : 0.f);
}

// BN + gelu: one wave per column, lane = row (64 rows)
__global__ __launch_bounds__(256) void bn_gelu_wave(
    const float* __restrict__ in, const float* __restrict__ g, const float* __restrict__ be,
    float* __restrict__ out, int C)
{
  int c = (blockIdx.x * blockDim.x + threadIdx.x) >> 6;
  int r = threadIdx.x & 63;
  if (c >= C) return;
  float v = in[(size_t)r * C + c];
  float s = v, q = v * v;
#pragma unroll
  for (int off = 32; off >= 1; off >>= 1) {
    s += __shfl_xor(s, off);
    q += __shfl_xor(q, off);
  }
  float m = s * (1.f / 64.f);
  float var = q * (1.f / 64.f) - m * m;
  float rs = rsqrtf(var + 1e-5f);
  out[(size_t)r * C + c] = gelu_f((v - m) * rs * g[c] + be[c]);
}

extern "C" void kernel_launch(void* const* d_in, const int* in_sizes, int n_in,
                              void* d_out, int out_size, void* d_ws, size_t ws_size,
                              hipStream_t stream)
{
  const float* x_in[3] = {(const float*)d_in[0], (const float*)d_in[1], (const float*)d_in[2]};
  const float* y_base = (const float*)d_in[3];
  const float* W_in = (const float*)d_in[4];
  const float* b_in = (const float*)d_in[5];
  const float* ln_g = (const float*)d_in[6];
  const float* ln_b = (const float*)d_in[7];
  const float* W_kqv = (const float*)d_in[8];
  const float* b_kqv = (const float*)d_in[9];
  const float* W_krel = (const float*)d_in[10];
  const float* W_vrel = (const float*)d_in[11];
  const float* p_rel = (const float*)d_in[12];
  const float* W_out = (const float*)d_in[13];
  const float* b_out = (const float*)d_in[14];
  const float* skipv = (const float*)d_in[15];
  const float* W_jk = (const float*)d_in[16];
  const float* b_jk = (const float*)d_in[17];
  const float* W_gate = (const float*)d_in[18];
  const float* b_gate = (const float*)d_in[19];
  const float* W_y1 = (const float*)d_in[20];
  const float* b_y1 = (const float*)d_in[21];
  const float* W_y2 = (const float*)d_in[22];
  const float* b_y2 = (const float*)d_in[23];
  const float* Wg1 = (const float*)d_in[24];
  const float* bg1 = (const float*)d_in[25];
  const float* g1 = (const float*)d_in[26];
  const float* beta1 = (const float*)d_in[27];
  const float* Wg2 = (const float*)d_in[28];
  const float* bg2 = (const float*)d_in[29];
  const float* g2 = (const float*)d_in[30];
  const float* beta2 = (const float*)d_in[31];
  const float* Wg3 = (const float*)d_in[32];
  const float* bg3 = (const float*)d_in[33];
  const int* eis[4] = {(const int*)d_in[34], (const int*)d_in[35], (const int*)d_in[36], (const int*)d_in[37]};
  const int* batchp[3] = {(const int*)d_in[38], (const int*)d_in[39], (const int*)d_in[40]};

  const int NSs[3] = {NS0, NS1, NS2};
  const int offs[3] = {0, OFF1, OFF2};
  const int NEs[4] = {320000, 320000, 160000, 160000};
  const int stt[4] = {0, 1, 0, 2};
  const int dtt[4] = {1, 0, 2, 0};
  const size_t scoff[4] = {0, 320000, 640000, 800000};
  const size_t vroff[4] = {0, 80000, 140000, 220000};
  const int ndst[4] = {60000, 80000, 30000, 80000};

  float* ws = nullptr;
  if (hipGetSymbolAddress((void**)&ws, HIP_SYMBOL(g_ws)) != hipSuccess || !ws) return;

  const size_t NODE = (size_t)NTOT * 256;
  size_t o = 0;
  float* Xcur = ws + o;  o += NODE;
  float* Hb = ws + o;    o += NODE;
  float* TMPo = ws + o;  o += NODE;
  float* JKacc = ws + o; o += NODE;
  float* SC = ws + o;    o += (size_t)960000 * 4;
  float* GS = ws + o;    o += (size_t)NTOT;
  float* MZ = ws + o;    o += 128;
  float* O784 = ws + o;  o += (size_t)64 * 784;
  float* BN1 = ws + o;   o += (size_t)64 * 256;
  float* T1 = ws + o;    o += (size_t)64 * 256;
  float* BN2 = ws + o;   o += (size_t)64 * 128;
  float* T2 = ws + o;    o += (size_t)64 * 128;
  float* WT1f = ws + o;  o += (size_t)256 * 784;
  float* WT2f = ws + o;  o += (size_t)128 * 256;
  // bf16 buffers (float units)
  ushort* QKV = (ushort*)(ws + o);     o += (size_t)NTOT * 768 / 2;
  ushort* Hb_bf = (ushort*)(ws + o);   o += NODE / 2;
  ushort* Xcur_bf = (ushort*)(ws + o); o += NODE / 2;
  ushort* AGGb = (ushort*)(ws + o);    o += NODE / 2;
  ushort* KRb = (ushort*)(ws + o);     o += (size_t)80000 * 256 / 2;
  ushort* VRb = (ushort*)(ws + o);     o += (size_t)250000 * 256 / 2;
  ushort* Xin_bf = (ushort*)(ws + o);  o += (size_t)NTOT * 128 / 2;
  ushort* WT_in = (ushort*)(ws + o);   o += (size_t)3 * 256 * 128 / 2;
  ushort* WT_kqv = (ushort*)(ws + o);  o += (size_t)12 * 768 * 256 / 2;
  ushort* WT_krel = (ushort*)(ws + o); o += (size_t)16 * 256 * 256 / 2;
  ushort* WT_vrel = (ushort*)(ws + o); o += (size_t)16 * 256 * 256 / 2;
  ushort* WT_out = (ushort*)(ws + o);  o += (size_t)12 * 256 * 256 / 2;
  ushort* WT_jk = (ushort*)(ws + o);   o += (size_t)3 * 256 * 1024 / 2;
  // int region (kept last)
  int* ib = (int*)(ws + o);
  size_t io = 0;
  int* rp[4]; int* srcc[4]; int* dstc[4]; int* degc[4];
  for (int e = 0; e < 4; ++e) { rp[e] = ib + io; io += ndst[e] + 1; }
  for (int e = 0; e < 4; ++e) { srcc[e] = ib + io; io += NEs[e]; }
  for (int e = 0; e < 4; ++e) { dstc[e] = ib + io; io += NEs[e]; }
  for (int e = 0; e < 4; ++e) { degc[e] = ib + io; io += ndst[e]; }
  int* bsum = ib + io; io += 257;
  int* bptr3 = ib + io; io += 3 * 65;

  auto gemm = [&](const ushort* A, int lda, const ushort* BT, int ldb, const float* bias,
                  float* Cf, ushort* Cb, int ldc, int M, int N, int K, int accum) {
    dim3 g((M + 127) / 128, N / 128);
    gemm_mfma<<<g, 256, 0, stream>>>(A, lda, BT, ldb, bias, Cf, Cb, ldc, M, K, accum);
  };

  // ---- weight transpose + bf16 convert ----
  wtrans<<<dim3(4, 8, 3), 256, 0, stream>>>(W_in, WT_in, 128, 256);
  wtrans<<<dim3(8, 24, 12), 256, 0, stream>>>(W_kqv, WT_kqv, 256, 768);
  wtrans<<<dim3(8, 8, 16), 256, 0, stream>>>(W_krel, WT_krel, 256, 256);
  wtrans<<<dim3(8, 8, 16), 256, 0, stream>>>(W_vrel, WT_vrel, 256, 256);
  wtrans<<<dim3(8, 8, 12), 256, 0, stream>>>(W_out, WT_out, 256, 256);
  wtrans<<<dim3(32, 8, 3), 256, 0, stream>>>(W_jk, WT_jk, 1024, 256);
  wtrans_f32<<<dim3(25, 8), 256, 0, stream>>>(Wg1, WT1f, 784, 256);
  wtrans_f32<<<dim3(8, 4), 256, 0, stream>>>(Wg2, WT2f, 256, 128);

  for (int i = 0; i < 3; ++i) {
    int n4 = NSs[i] * 128 / 4;
    conv_bf16<<<(n4 + 255) / 256, 256, 0, stream>>>(x_in[i], Xin_bf + (size_t)offs[i] * 128, n4);
  }

  // ---- CSR per edge type ----
  for (int e = 0; e < 4; ++e) {
    int n = ndst[e], ne = NEs[e];
    int nb = (n + 1023) / 1024;
    hipMemsetAsync(degc[e], 0, n * sizeof(int), stream);
    csr_hist<<<(ne + 255) / 256, 256, 0, stream>>>(eis[e], ne, degc[e]);
    scan_block<<<nb, 256, 0, stream>>>(degc[e], n, rp[e], bsum);
    scan_bsum<<<1, 1, 0, stream>>>(bsum, nb);
    scan_add<<<(n + 256) / 256, 256, 0, stream>>>(rp[e], n, bsum, nb);
    hipMemsetAsync(degc[e], 0, n * sizeof(int), stream);
    csr_scatter<<<(ne + 255) / 256, 256, 0, stream>>>(eis[e], ne, rp[e], degc[e], srcc[e], dstc[e]);
  }
  for (int i = 0; i < 3; ++i)
    batch_ptr<<<1, 128, 0, stream>>>(batchp[i], NSs[i], bptr3 + i * 65);

  // ---- input projection -> Xcur (f32) ----
  for (int i = 0; i < 3; ++i)
    gemm(Xin_bf + (size_t)offs[i] * 128, 128, WT_in + (size_t)i * 256 * 128, 128,
         b_in + i * 256, Xcur + (size_t)offs[i] * 256, nullptr, 256, NSs[i], 256, 128, 0);

  for (int l = 0; l < 4; ++l) {
    ln_kernel<<<(NTOT * 64 + 255) / 256, 256, 0, stream>>>(
        Xcur, ln_g + (size_t)l * 3 * 256, ln_b + (size_t)l * 3 * 256, Hb, Hb_bf);

    for (int i = 0; i < 3; ++i)
      gemm(Hb_bf + (size_t)offs[i] * 256, 256,
           WT_kqv + ((size_t)l * 3 + i) * 768 * 256, 256,
           b_kqv + ((size_t)l * 3 + i) * 768,
           nullptr, QKV + (size_t)offs[i] * 768, 768, NSs[i], 768, 256, 0);

    for (int e = 0; e < 4; ++e) {
      gemm(QKV + (size_t)offs[stt[e]] * 768, 768,
           WT_krel + ((size_t)l * 4 + e) * 256 * 256, 256, nullptr,
           nullptr, KRb, 256, NSs[stt[e]], 256, 256, 0);
      edge_scores<<<(NEs[e] * 64 + 255) / 256, 256, 0, stream>>>(
          srcc[e], dstc[e], NEs[e], QKV, offs[dtt[e]], KRb,
          p_rel + ((size_t)l * 4 + e) * 4, SC, scoff[e]);
    }

    node_softmax<<<(NS0 * 4 + 255) / 256, 256, 0, stream>>>(
        NS0, rp[1], scoff[1], rp[3], scoff[3], SC);
    node_softmax<<<(NS1 * 4 + 255) / 256, 256, 0, stream>>>(
        NS1, rp[0], scoff[0], nullptr, 0, SC);
    node_softmax<<<(NS2 * 4 + 255) / 256, 256, 0, stream>>>(
        NS2, rp[2], scoff[2], nullptr, 0, SC);

    for (int e = 0; e < 4; ++e)
      gemm(QKV + (size_t)offs[stt[e]] * 768 + 512, 768,
           WT_vrel + ((size_t)l * 4 + e) * 256 * 256, 256, nullptr,
           nullptr, VRb + vroff[e] * 256, 256, NSs[stt[e]], 256, 256, 0);

    node_aggr<<<(NS0 + 3) / 4, 256, 0, stream>>>(
        NS0, 0,
        rp[1], srcc[1], scoff[1], VRb + vroff[1] * 256,
        rp[3], srcc[3], scoff[3], VRb + vroff[3] * 256,
        SC, AGGb);
    node_aggr<<<(NS1 + 3) / 4, 256, 0, stream>>>(
        NS1, OFF1,
        rp[0], srcc[0], scoff[0], VRb + vroff[0] * 256,
        nullptr, nullptr, 0, nullptr,
        SC, AGGb);
    node_aggr<<<(NS2 + 3) / 4, 256, 0, stream>>>(
        NS2, OFF2,
        rp[2], srcc[2], scoff[2], VRb + vroff[2] * 256,
        nullptr, nullptr, 0, nullptr,
        SC, AGGb);

    for (int i = 0; i < 3; ++i)
      gemm(AGGb + (size_t)offs[i] * 256, 256,
           WT_out + ((size_t)l * 3 + i) * 256 * 256, 256,
           b_out + ((size_t)l * 3 + i) * 256,
           TMPo + (size_t)offs[i] * 256, nullptr, 256, NSs[i], 256, 256, 0);

    skip_store<<<(NTOT * 64 + 255) / 256, 256, 0, stream>>>(
        TMPo, Hb, skipv + l * 3, Xcur, Xcur_bf);

    for (int i = 0; i < 3; ++i)
      gemm(Xcur_bf + (size_t)offs[i] * 256, 256,
           WT_jk + (size_t)i * 256 * 1024 + (size_t)l * 256, 1024,
           (l == 0) ? (b_jk + i * 256) : nullptr,
           JKacc + (size_t)offs[i] * 256, nullptr, 256, NSs[i], 256, 256, (l == 0) ? 0 : 1);
  }

  // ---- gated pooling ----
  hipMemsetAsync(O784, 0, (size_t)64 * 784 * sizeof(float), stream);
  for (int i = 0; i < 3; ++i)
    gate_score<<<(NSs[i] * 64 + 255) / 256, 256, 0, stream>>>(
        JKacc + (size_t)offs[i] * 256, W_gate + i * 256, b_gate + i, GS + offs[i], NSs[i]);
  for (int i = 0; i < 3; ++i) {
    pool_mz<<<64, 256, 0, stream>>>(GS + offs[i], bptr3 + i * 65, MZ);
    pool_partial<<<dim3(64, NCHUNK), 256, 0, stream>>>(
        JKacc + (size_t)offs[i] * 256, GS + offs[i], bptr3 + i * 65, MZ, O784, i * 256);
  }

  hy_kernel<<<1, 64, 0, stream>>>(y_base, W_y1, b_y1, W_y2, b_y2, O784);

  // ---- head MLP: wave-parallel ----
  dense_wave<<<(64 * 256 + 3) / 4, 256, 0, stream>>>(O784, WT1f, bg1, BN1, 64, 256, 784);
  bn_gelu_wave<<<(256 + 3) / 4, 256, 0, stream>>>(BN1, g1, beta1, T1, 256);
  dense_wave<<<(64 * 128 + 3) / 4, 256, 0, stream>>>(T1, WT2f, bg2, BN2, 64, 128, 256);
  bn_gelu_wave<<<(128 + 3) / 4, 256, 0, stream>>>(BN2, g2, beta2, T2, 128);
  dense_wave<<<(64 * 1 + 3) / 4, 256, 0, stream>>>(T2, Wg3, bg3, (float*)d_out, 64, 1, 128);
}